// Round 15
// baseline (8217.761 us; speedup 1.0000x reference)
//
#include <hip/hip_runtime.h>
#include <cstddef>
#include <cstdint>

constexpr int B  = 48;
constexpr int L  = 192;
constexpr int T  = 193;    // L + 1
constexpr int KD = 1024;   // I == H
constexpr int G3 = 3072;   // 3*H
constexpr int V  = 8192;
constexpr int M  = T * B;  // 9264
constexpr int SB = 128;    // scan blocks per layer: 8 h-channels each

// dynamic LDS layout (bytes) for the persistent scan
constexpr int OFF_HI = 0;            // 24*1024*2 = 49152
constexpr int OFF_LO = 49152;
constexpr int OFF_WX = 98304;
constexpr int OFF_CP = 147456;       // 2*48*33*4 = 12672
constexpr int LDS_TOTAL = 160128;    // <= 163840

typedef float f32x4 __attribute__((ext_vector_type(4)));
typedef short s16x8 __attribute__((ext_vector_type(8)));
typedef unsigned short u16x8 __attribute__((ext_vector_type(8)));

__device__ inline unsigned short f2bf(float f) {
  unsigned u = __builtin_bit_cast(unsigned, f);
  u += 0x7fffu + ((u >> 16) & 1u);   // round-to-nearest-even
  return (unsigned short)(u >> 16);
}
__device__ inline float bf2f(unsigned short h) {
  return __builtin_bit_cast(float, (unsigned)h << 16);
}

// LLC-coherent 16B load / 2B store: agent-scope relaxed atomics bypass the
// incoherent L1/L2 and hit the shared Infinity Cache. No fences needed.
__device__ inline s16x8 ld_sc16(const unsigned short* p) {
  unsigned long long lo = __hip_atomic_load((const unsigned long long*)p,
                                            __ATOMIC_RELAXED, __HIP_MEMORY_SCOPE_AGENT);
  unsigned long long hi = __hip_atomic_load((const unsigned long long*)p + 1,
                                            __ATOMIC_RELAXED, __HIP_MEMORY_SCOPE_AGENT);
  struct { unsigned long long a, b; } u{lo, hi};
  return __builtin_bit_cast(s16x8, u);
}
__device__ inline void st_sc2(unsigned short* p, unsigned short v) {
  __hip_atomic_store(p, v, __ATOMIC_RELAXED, __HIP_MEMORY_SCOPE_AGENT);
}

// ---------------------------------------------------------------------------
__global__ __launch_bounds__(256)
void init_h0(const float* __restrict__ et, const int* __restrict__ ids,
             float* __restrict__ h0f, unsigned short* __restrict__ h0hi,
             unsigned short* __restrict__ h0lo) {
  int b = blockIdx.x;
  int id = ids[b];
  float4 v = ((const float4*)(et + (size_t)id * KD))[threadIdx.x];
  ((float4*)(h0f + (size_t)b * KD))[threadIdx.x] = v;
  int base = b * KD + threadIdx.x * 4;
  float vv[4] = {v.x, v.y, v.z, v.w};
#pragma unroll
  for (int j = 0; j < 4; ++j) {
    unsigned short hi = f2bf(vv[j]);
    h0hi[base + j] = hi;
    h0lo[base + j] = f2bf(vv[j] - bf2f(hi));
  }
}

// fp32 -> bf16 (raw bits), 8 elems/thread
__global__ __launch_bounds__(256)
void cvt_bf16(const float* __restrict__ in, unsigned short* __restrict__ out,
              long long n) {
  long long i = ((long long)blockIdx.x * 256 + threadIdx.x) * 8;
  if (i + 8 > n) return;
  float4 v0 = *(const float4*)(in + i);
  float4 v1 = *(const float4*)(in + i + 4);
  u16x8 o;
  o[0] = f2bf(v0.x); o[1] = f2bf(v0.y); o[2] = f2bf(v0.z); o[3] = f2bf(v0.w);
  o[4] = f2bf(v1.x); o[5] = f2bf(v1.y); o[6] = f2bf(v1.z); o[7] = f2bf(v1.w);
  *(u16x8*)(out + i) = o;
}

// ---------------------------------------------------------------------------
// Repack [3*KD, KD] fp32 weights -> per-block split-bf16 [SB][32][KD] (hi,lo).
__global__ __launch_bounds__(256)
void repack_whh(const float* __restrict__ w_hh, unsigned short* __restrict__ hi,
                unsigned short* __restrict__ lo) {
  long long idx = ((long long)blockIdx.x * 256 + threadIdx.x) * 8;
  if (idx >= (long long)SB * 32 * KD) return;
  int k  = (int)(idx & (KD - 1));
  int rr = (int)(idx >> 10);
  int r = rr & 31, bid = rr >> 5;
  u16x8 h8 = (u16x8)0, l8 = (u16x8)0;
  if (r < 24) {
    int g = r >> 3, c = bid * 8 + (r & 7);
    const float* src = w_hh + ((size_t)(g * KD + c)) * KD + k;
    float4 v0 = *(const float4*)src, v1 = *(const float4*)(src + 4);
    float vv[8] = {v0.x, v0.y, v0.z, v0.w, v1.x, v1.y, v1.z, v1.w};
#pragma unroll
    for (int j = 0; j < 8; ++j) {
      unsigned short h = f2bf(vv[j]);
      h8[j] = h;
      l8[j] = f2bf(vv[j] - bf2f(h));
    }
  }
  *(u16x8*)(hi + idx) = h8;
  *(u16x8*)(lo + idx) = l8;
}

// Same packing, single bf16 (for w_ih1 used by the on-the-fly x-projection).
__global__ __launch_bounds__(256)
void repack_w_single(const float* __restrict__ w, unsigned short* __restrict__ pk) {
  long long idx = ((long long)blockIdx.x * 256 + threadIdx.x) * 8;
  if (idx >= (long long)SB * 32 * KD) return;
  int k  = (int)(idx & (KD - 1));
  int rr = (int)(idx >> 10);
  int r = rr & 31, bid = rr >> 5;
  u16x8 h8 = (u16x8)0;
  if (r < 24) {
    int g = r >> 3, c = bid * 8 + (r & 7);
    const float* src = w + ((size_t)(g * KD + c)) * KD + k;
    float4 v0 = *(const float4*)src, v1 = *(const float4*)(src + 4);
    float vv[8] = {v0.x, v0.y, v0.z, v0.w, v1.x, v1.y, v1.z, v1.w};
#pragma unroll
    for (int j = 0; j < 8; ++j) h8[j] = f2bf(vv[j]);
  }
  *(u16x8*)(pk + idx) = h8;
}

// ---------------------------------------------------------------------------
// bf16 MFMA GEMM (validated R2/R7): C[m,n] = sum_k A[m,k]*W[n,k] + bias[n].
template<int GATHER, int OUTMODE>
__global__ __launch_bounds__(256)
void gemm_bf16(const unsigned short* __restrict__ A,
               const unsigned short* __restrict__ W,
               const float* __restrict__ bias, float* __restrict__ C, int Ndim,
               const int* __restrict__ seq,
               const unsigned short* __restrict__ start_bf,
               const unsigned short* __restrict__ table_bf) {
  __shared__ __align__(16) unsigned short a_s[128 * 32];
  __shared__ __align__(16) unsigned short b_s[128 * 32];
  const int tid  = threadIdx.x;
  const int lane = tid & 63;
  const int wave = tid >> 6;
  const int m0 = blockIdx.x * 128;
  const int n0 = blockIdx.y * 128;
  const int wr = wave >> 1, wc = wave & 1;

  f32x4 acc[4][4];
#pragma unroll
  for (int i = 0; i < 4; ++i)
#pragma unroll
    for (int j = 0; j < 4; ++j) acc[i][j] = (f32x4){0.f, 0.f, 0.f, 0.f};

  const int lrow = lane & 15;
  const int lkhi = lane >> 4;

  for (int kt = 0; kt < KD; kt += 32) {
    __syncthreads();
#pragma unroll
    for (int j = 0; j < 2; ++j) {
      int flat = tid * 16 + j * 4096;
      int row = flat >> 6;
      int cc = (flat >> 4) & 3;
      const unsigned short* src;
      if (GATHER) {
        int m = m0 + row; if (m >= M) m = 0;
        int t = m / B, b = m - t * B;
        const unsigned short* rowsrc =
            (t == 0) ? start_bf : (table_bf + (size_t)seq[b * L + t - 1] * KD);
        src = rowsrc + kt + cc * 8;
      } else {
        int m = m0 + row; if (m >= M) m = 0;
        src = A + (size_t)m * KD + kt + cc * 8;
      }
      *(int4*)((char*)a_s + flat) = *(const int4*)src;
    }
#pragma unroll
    for (int j = 0; j < 2; ++j) {
      int flat = tid * 16 + j * 4096;
      int row = flat >> 6;
      int cc = (flat >> 4) & 3;
      const unsigned short* src = W + (size_t)(n0 + row) * KD + kt + cc * 8;
      *(int4*)((char*)b_s + flat) = *(const int4*)src;
    }
    __syncthreads();

    s16x8 af[4], wf[4];
#pragma unroll
    for (int i = 0; i < 4; ++i) {
      int arow = wr * 64 + i * 16 + lrow;
      af[i] = *(const s16x8*)((const char*)a_s + arow * 64 + lkhi * 16);
      int brow = wc * 64 + i * 16 + lrow;
      wf[i] = *(const s16x8*)((const char*)b_s + brow * 64 + lkhi * 16);
    }
#pragma unroll
    for (int i = 0; i < 4; ++i)
#pragma unroll
      for (int j = 0; j < 4; ++j)
        acc[i][j] = __builtin_amdgcn_mfma_f32_16x16x32_bf16(af[i], wf[j],
                                                            acc[i][j], 0, 0, 0);
  }

#pragma unroll
  for (int i = 0; i < 4; ++i) {
#pragma unroll
    for (int r = 0; r < 4; ++r) {
      int m = m0 + wr * 64 + i * 16 + (lane >> 4) * 4 + r;
      if (m >= M) continue;
      size_t rowoff;
      if (OUTMODE == 0) {
        rowoff = (size_t)m * (size_t)Ndim;
      } else {
        int t = m / B, b = m - t * B;
        rowoff = ((size_t)b * T + t) * (size_t)Ndim;
      }
#pragma unroll
      for (int j = 0; j < 4; ++j) {
        int n = n0 + wc * 64 + j * 16 + (lane & 15);
        C[rowoff + n] = acc[i][j][r] + bias[n];
      }
    }
  }
}

// ---------------------------------------------------------------------------
// Persistent pipelined two-layer scan: LDS-resident weights (R13, fence-immune)
// + fence-free LLC h-exchange and single-hop barrier (R14).
// Iteration t: blocks [0,SB) do layer0 step t; [SB,2SB) do layer1 step t-1.
struct ScanArgs {
  const float* xp0;
  const unsigned short* wpk0_hi; const unsigned short* wpk0_lo; const float* b_hh0;
  const unsigned short* wpk1_hi; const unsigned short* wpk1_lo;
  const unsigned short* wih1pk;  const float* b_ih1; const float* b_hh1;
  const unsigned short* h0hi;    const unsigned short* h0lo; const float* h0f;
  unsigned short* ys0_bf; unsigned short* lo0a; unsigned short* lo0b; float* h0f32;
  unsigned short* ys1_bf; unsigned short* lo1a; unsigned short* lo1b; float* h1f32;
  unsigned* flags;
};

__global__ __launch_bounds__(256, 1)
void gru_scan_persist(ScanArgs a) {
  extern __shared__ __align__(16) char smem[];
  unsigned short* s_hi = (unsigned short*)(smem + OFF_HI);
  unsigned short* s_lo = (unsigned short*)(smem + OFF_LO);
  unsigned short* s_wx = (unsigned short*)(smem + OFF_WX);
  float* cp = (float*)(smem + OFF_CP);   // [2][48*33]

  const int tid = threadIdx.x;
  const bool is1 = blockIdx.x >= SB;
  const int bid = is1 ? (int)blockIdx.x - SB : (int)blockIdx.x;
  const int c0 = bid * 8;
  const int lane = tid & 63, wave = tid >> 6;
  const int lrow = lane & 15, lkhi = lane >> 4;
  const int kh = wave >> 1, ntw = wave & 1;   // K-half, n-tile per wave

  // ---- one-time: stage weights into LDS, 16B-chunk XOR swizzle on (row&7)
  {
    const unsigned short* g_hi = (is1 ? a.wpk1_hi : a.wpk0_hi) + (size_t)bid * 32 * KD;
    const unsigned short* g_lo = (is1 ? a.wpk1_lo : a.wpk0_lo) + (size_t)bid * 32 * KD;
    const unsigned short* g_wx = a.wih1pk + (size_t)bid * 32 * KD;
    for (int i = tid; i < 24 * 128; i += 256) {
      int r = i >> 7, c16 = i & 127;
      int d = (r * 128 + (c16 ^ (r & 7))) * 8;
      *(u16x8*)(s_hi + d) = *(const u16x8*)(g_hi + (size_t)r * KD + c16 * 8);
      *(u16x8*)(s_lo + d) = *(const u16x8*)(g_lo + (size_t)r * KD + c16 * 8);
      if (is1) *(u16x8*)(s_wx + d) = *(const u16x8*)(g_wx + (size_t)r * KD + c16 * 8);
    }
  }
  __syncthreads();

  int rB = ntw * 16 + lrow; if (rB > 23) rB = 23;   // clamp pad rows
  const int rsw = rB & 7;

  for (int t = 0; t <= T; ++t) {
    int s = is1 ? t - 1 : t;
    bool active = is1 ? (s >= 0) : (s < T);
    if (active) {
      const unsigned short *Shi, *Slo, *Xhi = nullptr;
      const float *hold, *bhh, *xp_t = nullptr;
      float* hnew_p;
      unsigned short *yhi, *ylo;
      if (!is1) {
        Shi = (s == 0) ? a.h0hi : a.ys0_bf + (size_t)(s - 1) * B * KD;
        Slo = (s == 0) ? a.h0lo : (((s - 1) & 1) ? a.lo0b : a.lo0a);
        hold = (s == 0) ? a.h0f : a.h0f32;
        hnew_p = a.h0f32;
        yhi = a.ys0_bf + (size_t)s * B * KD;
        ylo = (s & 1) ? a.lo0b : a.lo0a;
        bhh = a.b_hh0;
        xp_t = a.xp0 + (size_t)s * B * G3;
      } else {
        Shi = (s == 0) ? a.h0hi : a.ys1_bf + (size_t)(s - 1) * B * KD;
        Slo = (s == 0) ? a.h0lo : (((s - 1) & 1) ? a.lo1b : a.lo1a);
        hold = (s == 0) ? a.h0f : a.h1f32;
        hnew_p = a.h1f32;
        yhi = a.ys1_bf + (size_t)s * B * KD;
        ylo = (s & 1) ? a.lo1b : a.lo1a;
        bhh = a.b_hh1;
        Xhi = a.ys0_bf + (size_t)s * B * KD;
      }

      f32x4 acch[3], accx[3];
#pragma unroll
      for (int mt = 0; mt < 3; ++mt) {
        acch[mt] = (f32x4){0.f, 0.f, 0.f, 0.f};
        accx[mt] = (f32x4){0.f, 0.f, 0.f, 0.f};
      }

#pragma unroll 4
      for (int ks = 0; ks < 16; ++ks) {
        int k0 = kh * 512 + ks * 32 + lkhi * 8;
        int c16 = k0 >> 3;
        int off = (rB * 128 + (c16 ^ rsw)) * 8;
        s16x8 bh = *(const s16x8*)(s_hi + off);
        s16x8 bl = *(const s16x8*)(s_lo + off);
        s16x8 wx;
        if (is1) wx = *(const s16x8*)(s_wx + off);
#pragma unroll
        for (int mt = 0; mt < 3; ++mt) {
          int b = mt * 16 + lrow;
          s16x8 ah = ld_sc16(Shi + (size_t)b * KD + k0);
          s16x8 al = ld_sc16(Slo + (size_t)b * KD + k0);
          acch[mt] = __builtin_amdgcn_mfma_f32_16x16x32_bf16(ah, bh, acch[mt], 0, 0, 0);
          acch[mt] = __builtin_amdgcn_mfma_f32_16x16x32_bf16(al, bh, acch[mt], 0, 0, 0);
          acch[mt] = __builtin_amdgcn_mfma_f32_16x16x32_bf16(ah, bl, acch[mt], 0, 0, 0);
          if (is1) {
            s16x8 xh = ld_sc16(Xhi + (size_t)b * KD + k0);
            accx[mt] = __builtin_amdgcn_mfma_f32_16x16x32_bf16(xh, wx, accx[mt], 0, 0, 0);
          }
        }
      }

      // phase 1: h partials through cp
#pragma unroll
      for (int mt = 0; mt < 3; ++mt)
#pragma unroll
        for (int r = 0; r < 4; ++r) {
          int row = mt * 16 + (lane >> 4) * 4 + r;
          cp[(kh * 48 + row) * 33 + ntw * 16 + (lane & 15)] = acch[mt][r];
        }
      __syncthreads();
      float ph[2][3];
#pragma unroll
      for (int i = 0; i < 2; ++i) {
        int p = tid + i * 256;
        if (p < 384) {
          int b = p >> 3, c = p & 7;
          ph[i][0] = cp[b * 33 + c]      + cp[(48 + b) * 33 + c];
          ph[i][1] = cp[b * 33 + 8 + c]  + cp[(48 + b) * 33 + 8 + c];
          ph[i][2] = cp[b * 33 + 16 + c] + cp[(48 + b) * 33 + 16 + c];
        }
      }
      // phase 2 (layer1): x partials through the same cp buffer
      float px[2][3];
      if (is1) {
        __syncthreads();
#pragma unroll
        for (int mt = 0; mt < 3; ++mt)
#pragma unroll
          for (int r = 0; r < 4; ++r) {
            int row = mt * 16 + (lane >> 4) * 4 + r;
            cp[(kh * 48 + row) * 33 + ntw * 16 + (lane & 15)] = accx[mt][r];
          }
        __syncthreads();
#pragma unroll
        for (int i = 0; i < 2; ++i) {
          int p = tid + i * 256;
          if (p < 384) {
            int b = p >> 3, c = p & 7;
            px[i][0] = cp[b * 33 + c]      + cp[(48 + b) * 33 + c];
            px[i][1] = cp[b * 33 + 8 + c]  + cp[(48 + b) * 33 + 8 + c];
            px[i][2] = cp[b * 33 + 16 + c] + cp[(48 + b) * 33 + 16 + c];
          }
        }
      }

      // gate + state update
#pragma unroll
      for (int i = 0; i < 2; ++i) {
        int p = tid + i * 256;
        if (p >= 384) break;
        int b = p >> 3, c = p & 7;
        int gc = c0 + c;
        float xr, xz, xn;
        if (is1) {
          xr = px[i][0] + a.b_ih1[gc];
          xz = px[i][1] + a.b_ih1[KD + gc];
          xn = px[i][2] + a.b_ih1[2 * KD + gc];
        } else {
          const float* xrow = xp_t + (size_t)b * G3;
          xr = xrow[gc]; xz = xrow[KD + gc]; xn = xrow[2 * KD + gc];
        }
        float hr = ph[i][0] + bhh[gc];
        float hz = ph[i][1] + bhh[KD + gc];
        float hn = ph[i][2] + bhh[2 * KD + gc];
        float r_ = 1.f / (1.f + expf(-(xr + hr)));
        float z_ = 1.f / (1.f + expf(-(xz + hz)));
        float n_ = tanhf(xn + r_ * hn);
        float hv = hold[(size_t)b * KD + gc];
        float hnew = (1.f - z_) * n_ + z_ * hv;
        hnew_p[(size_t)b * KD + gc] = hnew;     // block-private, normal cached
        unsigned short hi = f2bf(hnew);
        st_sc2(yhi + (size_t)b * KD + gc, hi);  // cross-read -> LLC
        st_sc2(ylo + (size_t)b * KD + gc, f2bf(hnew - bf2f(hi)));
      }
    }

    // single-hop fence-free barrier (validated R14): drain vmem, flag, poll.
    asm volatile("s_waitcnt vmcnt(0)" ::: "memory");
    __syncthreads();
    if (tid == 0)
      __hip_atomic_store(a.flags + (size_t)blockIdx.x * 32, (unsigned)(t + 1),
                         __ATOMIC_RELAXED, __HIP_MEMORY_SCOPE_AGENT);
    {
      int spins = 0;
      while (__hip_atomic_load(a.flags + (size_t)tid * 32,
                               __ATOMIC_RELAXED, __HIP_MEMORY_SCOPE_AGENT)
             < (unsigned)(t + 1)) {
        if (++spins > (1 << 18)) break;   // failsafe: never hang
        __builtin_amdgcn_s_sleep(1);
      }
    }
    __syncthreads();
    asm volatile("" ::: "memory");
  }
}

// ---------------------------------------------------------------------------
__global__ __launch_bounds__(256)
void softmax_mask(float* __restrict__ out, const int* __restrict__ seq) {
  const int t = blockIdx.x, b = blockIdx.y;
  float* row = out + ((size_t)b * T + t) * V;
  __shared__ unsigned bits[V / 32];
  __shared__ float red[4];
  const int tid = threadIdx.x;
  const bool masked = (t < L - 1);
  if (masked) {
    bits[tid] = 0u;
    __syncthreads();
    int rem = L - t;
    if (tid < rem) {
      int id = seq[b * L + t + tid];
      atomicOr(&bits[id >> 5], 1u << (id & 31));
    }
  }
  __syncthreads();

  float4 x[8];
  float mx = -3.0e38f;
#pragma unroll
  for (int j = 0; j < 8; ++j) {
    float4 v = ((const float4*)row)[j * 256 + tid];
    if (masked) {
      int vb = (j * 256 + tid) * 4;
      unsigned wrd = bits[vb >> 5];
      int sh = vb & 31;
      if (!((wrd >> (sh + 0)) & 1u)) v.x = -1.0e30f;
      if (!((wrd >> (sh + 1)) & 1u)) v.y = -1.0e30f;
      if (!((wrd >> (sh + 2)) & 1u)) v.z = -1.0e30f;
      if (!((wrd >> (sh + 3)) & 1u)) v.w = -1.0e30f;
    }
    x[j] = v;
    mx = fmaxf(mx, fmaxf(fmaxf(v.x, v.y), fmaxf(v.z, v.w)));
  }
#pragma unroll
  for (int off = 32; off > 0; off >>= 1) mx = fmaxf(mx, __shfl_xor(mx, off));
  int wv = tid >> 6;
  if ((tid & 63) == 0) red[wv] = mx;
  __syncthreads();
  mx = fmaxf(fmaxf(red[0], red[1]), fmaxf(red[2], red[3]));

  float s = 0.f;
#pragma unroll
  for (int j = 0; j < 8; ++j) {
    x[j].x = expf(x[j].x - mx); x[j].y = expf(x[j].y - mx);
    x[j].z = expf(x[j].z - mx); x[j].w = expf(x[j].w - mx);
    s += x[j].x + x[j].y + x[j].z + x[j].w;
  }
#pragma unroll
  for (int off = 32; off > 0; off >>= 1) s += __shfl_xor(s, off);
  __syncthreads();
  if ((tid & 63) == 0) red[wv] = s;
  __syncthreads();
  s = red[0] + red[1] + red[2] + red[3];
  float inv = 1.f / s;
#pragma unroll
  for (int j = 0; j < 8; ++j) {
    float4 v = make_float4(x[j].x * inv, x[j].y * inv, x[j].z * inv, x[j].w * inv);
    ((float4*)row)[j * 256 + tid] = v;
  }
}

// ---------------------------------------------------------------------------
extern "C" void kernel_launch(void* const* d_in, const int* in_sizes, int n_in,
                              void* d_out, int out_size, void* d_ws, size_t ws_size,
                              hipStream_t stream) {
  const float* event_table = (const float*)d_in[0];
  const float* user_table  = (const float*)d_in[1];
  const float* startv      = (const float*)d_in[2];
  const float* w_ih0 = (const float*)d_in[3];
  const float* w_hh0 = (const float*)d_in[4];
  const float* b_ih0 = (const float*)d_in[5];
  const float* b_hh0 = (const float*)d_in[6];
  const float* w_ih1 = (const float*)d_in[7];
  const float* w_hh1 = (const float*)d_in[8];
  const float* b_ih1 = (const float*)d_in[9];
  const float* b_hh1 = (const float*)d_in[10];
  const float* lin_w = (const float*)d_in[11];
  const float* lin_b = (const float*)d_in[12];
  const int*   ids   = (const int*)d_in[13];
  const int*   seq   = (const int*)d_in[14];
  float* out = (float*)d_out;

  // workspace layout (~235 MB)
  float* xp0  = (float*)d_ws;                           // M*G3 f32
  float* h0f  = xp0 + (size_t)M * G3;                   // B*KD
  float* h0f32 = h0f + (size_t)B * KD;                  // B*KD (layer0 state)
  float* h1f32 = h0f32 + (size_t)B * KD;                // B*KD (layer1 state)
  unsigned short* ut_bf    = (unsigned short*)(h1f32 + (size_t)B * KD);
  unsigned short* start_bf = ut_bf    + (size_t)V * KD;
  unsigned short* wih0_bf  = start_bf + KD;
  unsigned short* linw_bf  = wih0_bf  + (size_t)G3 * KD;
  unsigned short* ys0_bf   = linw_bf  + (size_t)V * KD;
  unsigned short* ys1_bf   = ys0_bf   + (size_t)M * KD;
  unsigned short* h0hi     = ys1_bf   + (size_t)M * KD;
  unsigned short* h0lo     = h0hi + (size_t)B * KD;
  unsigned short* lo0a     = h0lo + (size_t)B * KD;
  unsigned short* lo0b     = lo0a + (size_t)B * KD;
  unsigned short* lo1a     = lo0b + (size_t)B * KD;
  unsigned short* lo1b     = lo1a + (size_t)B * KD;
  unsigned short* wpk0_hi  = lo1b + (size_t)B * KD;
  unsigned short* wpk0_lo  = wpk0_hi + (size_t)SB * 32 * KD;
  unsigned short* wpk1_hi  = wpk0_lo + (size_t)SB * 32 * KD;
  unsigned short* wpk1_lo  = wpk1_hi + (size_t)SB * 32 * KD;
  unsigned short* wih1pk   = wpk1_lo + (size_t)SB * 32 * KD;
  unsigned* flags          = (unsigned*)(wih1pk + (size_t)SB * 32 * KD);

  init_h0<<<dim3(B), 256, 0, stream>>>(event_table, ids, h0f, h0hi, h0lo);

  auto cvt = [&](const float* src, unsigned short* dst, long long n) {
    int blocks = (int)((n + 2047) / 2048);
    cvt_bf16<<<dim3(blocks), 256, 0, stream>>>(src, dst, n);
  };
  cvt(user_table, ut_bf,    (long long)V * KD);
  cvt(startv,     start_bf, KD);
  cvt(w_ih0,      wih0_bf,  (long long)G3 * KD);
  cvt(lin_w,      linw_bf,  (long long)V * KD);

  repack_whh<<<dim3(SB * 32 * KD / 2048), 256, 0, stream>>>(w_hh0, wpk0_hi, wpk0_lo);
  repack_whh<<<dim3(SB * 32 * KD / 2048), 256, 0, stream>>>(w_hh1, wpk1_hi, wpk1_lo);
  repack_w_single<<<dim3(SB * 32 * KD / 2048), 256, 0, stream>>>(w_ih1, wih1pk);

  // layer 0 input projection (gather from bf16 tables)
  gemm_bf16<1, 0><<<dim3((M + 127) / 128, G3 / 128), 256, 0, stream>>>(
      nullptr, wih0_bf, b_ih0, xp0, G3, seq, start_bf, ut_bf);

  // zero barrier flags, then persistent scan (dynamic LDS, fence-free)
  hipMemsetAsync(flags, 0, 2 * SB * 32 * sizeof(unsigned), stream);
  {
    hipFuncSetAttribute(reinterpret_cast<const void*>(gru_scan_persist),
                        hipFuncAttributeMaxDynamicSharedMemorySize, LDS_TOTAL);
    ScanArgs sa;
    sa.xp0 = xp0;
    sa.wpk0_hi = wpk0_hi; sa.wpk0_lo = wpk0_lo; sa.b_hh0 = b_hh0;
    sa.wpk1_hi = wpk1_hi; sa.wpk1_lo = wpk1_lo;
    sa.wih1pk = wih1pk;   sa.b_ih1 = b_ih1;     sa.b_hh1 = b_hh1;
    sa.h0hi = h0hi; sa.h0lo = h0lo; sa.h0f = h0f;
    sa.ys0_bf = ys0_bf; sa.lo0a = lo0a; sa.lo0b = lo0b; sa.h0f32 = h0f32;
    sa.ys1_bf = ys1_bf; sa.lo1a = lo1a; sa.lo1b = lo1b; sa.h1f32 = h1f32;
    sa.flags = flags;
    gru_scan_persist<<<dim3(2 * SB), dim3(256), LDS_TOTAL, stream>>>(sa);
  }

  // logits into d_out at [b][t][v]
  gemm_bf16<0, 1><<<dim3((M + 127) / 128, V / 128), 256, 0, stream>>>(
      ys1_bf, linw_bf, lin_b, out, V, nullptr, nullptr, nullptr);

  // masked softmax in place
  softmax_mask<<<dim3(T, B), 256, 0, stream>>>(out, seq);
}

// Round 16
// 4740.872 us; speedup vs baseline: 1.7334x; 1.7334x over previous
//
#include <hip/hip_runtime.h>
#include <cstddef>
#include <cstdint>

constexpr int B  = 48;
constexpr int L  = 192;
constexpr int T  = 193;    // L + 1
constexpr int KD = 1024;   // I == H
constexpr int G3 = 3072;   // 3*H
constexpr int V  = 8192;
constexpr int M  = T * B;  // 9264
constexpr int SB = 128;    // repack granularity: 8 h-channels per packed block
constexpr int NB = 64;     // scan blocks per layer (16 channels each)

typedef float f32x4 __attribute__((ext_vector_type(4)));
typedef short s16x8 __attribute__((ext_vector_type(8)));
typedef unsigned short u16x8 __attribute__((ext_vector_type(8)));

__device__ inline unsigned short f2bf(float f) {
  unsigned u = __builtin_bit_cast(unsigned, f);
  u += 0x7fffu + ((u >> 16) & 1u);   // round-to-nearest-even
  return (unsigned short)(u >> 16);
}
__device__ inline float bf2f(unsigned short h) {
  return __builtin_bit_cast(float, (unsigned)h << 16);
}

// ---------------------------------------------------------------------------
__global__ __launch_bounds__(256)
void init_h0(const float* __restrict__ et, const int* __restrict__ ids,
             float* __restrict__ h0f, unsigned short* __restrict__ h0hi,
             unsigned short* __restrict__ h0lo) {
  int b = blockIdx.x;
  int id = ids[b];
  float4 v = ((const float4*)(et + (size_t)id * KD))[threadIdx.x];
  ((float4*)(h0f + (size_t)b * KD))[threadIdx.x] = v;
  int base = b * KD + threadIdx.x * 4;
  float vv[4] = {v.x, v.y, v.z, v.w};
#pragma unroll
  for (int j = 0; j < 4; ++j) {
    unsigned short hi = f2bf(vv[j]);
    h0hi[base + j] = hi;
    h0lo[base + j] = f2bf(vv[j] - bf2f(hi));
  }
}

// fp32 -> bf16 (raw bits), 8 elems/thread
__global__ __launch_bounds__(256)
void cvt_bf16(const float* __restrict__ in, unsigned short* __restrict__ out,
              long long n) {
  long long i = ((long long)blockIdx.x * 256 + threadIdx.x) * 8;
  if (i + 8 > n) return;
  float4 v0 = *(const float4*)(in + i);
  float4 v1 = *(const float4*)(in + i + 4);
  u16x8 o;
  o[0] = f2bf(v0.x); o[1] = f2bf(v0.y); o[2] = f2bf(v0.z); o[3] = f2bf(v0.w);
  o[4] = f2bf(v1.x); o[5] = f2bf(v1.y); o[6] = f2bf(v1.z); o[7] = f2bf(v1.w);
  *(u16x8*)(out + i) = o;
}

// ---------------------------------------------------------------------------
// Repack [3*KD, KD] fp32 weights -> per-8ch-block split-bf16 [SB][32][KD].
__global__ __launch_bounds__(256)
void repack_whh(const float* __restrict__ w_hh, unsigned short* __restrict__ hi,
                unsigned short* __restrict__ lo) {
  long long idx = ((long long)blockIdx.x * 256 + threadIdx.x) * 8;
  if (idx >= (long long)SB * 32 * KD) return;
  int k  = (int)(idx & (KD - 1));
  int rr = (int)(idx >> 10);
  int r = rr & 31, bid = rr >> 5;
  u16x8 h8 = (u16x8)0, l8 = (u16x8)0;
  if (r < 24) {
    int g = r >> 3, c = bid * 8 + (r & 7);
    const float* src = w_hh + ((size_t)(g * KD + c)) * KD + k;
    float4 v0 = *(const float4*)src, v1 = *(const float4*)(src + 4);
    float vv[8] = {v0.x, v0.y, v0.z, v0.w, v1.x, v1.y, v1.z, v1.w};
#pragma unroll
    for (int j = 0; j < 8; ++j) {
      unsigned short h = f2bf(vv[j]);
      h8[j] = h;
      l8[j] = f2bf(vv[j] - bf2f(h));
    }
  }
  *(u16x8*)(hi + idx) = h8;
  *(u16x8*)(lo + idx) = l8;
}

// Same packing, single bf16 (w_ih1 for the on-the-fly x-projection).
__global__ __launch_bounds__(256)
void repack_w_single(const float* __restrict__ w, unsigned short* __restrict__ pk) {
  long long idx = ((long long)blockIdx.x * 256 + threadIdx.x) * 8;
  if (idx >= (long long)SB * 32 * KD) return;
  int k  = (int)(idx & (KD - 1));
  int rr = (int)(idx >> 10);
  int r = rr & 31, bid = rr >> 5;
  u16x8 h8 = (u16x8)0;
  if (r < 24) {
    int g = r >> 3, c = bid * 8 + (r & 7);
    const float* src = w + ((size_t)(g * KD + c)) * KD + k;
    float4 v0 = *(const float4*)src, v1 = *(const float4*)(src + 4);
    float vv[8] = {v0.x, v0.y, v0.z, v0.w, v1.x, v1.y, v1.z, v1.w};
#pragma unroll
    for (int j = 0; j < 8; ++j) h8[j] = f2bf(vv[j]);
  }
  *(u16x8*)(pk + idx) = h8;
}

// ---------------------------------------------------------------------------
// bf16 MFMA GEMM (validated R2/R7): C[m,n] = sum_k A[m,k]*W[n,k] + bias[n].
// SWZ=1: 1D grid with bijective XCD-chunk swizzle (nwg must be full tiles).
template<int GATHER, int OUTMODE, int SWZ>
__global__ __launch_bounds__(256)
void gemm_bf16(const unsigned short* __restrict__ A,
               const unsigned short* __restrict__ W,
               const float* __restrict__ bias, float* __restrict__ C, int Ndim,
               const int* __restrict__ seq,
               const unsigned short* __restrict__ start_bf,
               const unsigned short* __restrict__ table_bf) {
  __shared__ __align__(16) unsigned short a_s[128 * 32];
  __shared__ __align__(16) unsigned short b_s[128 * 32];
  const int tid  = threadIdx.x;
  const int lane = tid & 63;
  const int wave = tid >> 6;
  int m0, n0;
  if (SWZ) {
    const int nwg = gridDim.x;
    const int q = nwg >> 3, r8 = nwg & 7;
    const int xcd = blockIdx.x & 7, oidx = blockIdx.x >> 3;
    const int wgid = (xcd < r8 ? xcd * (q + 1) : r8 * (q + 1) + (xcd - r8) * q) + oidx;
    const int nby = Ndim >> 7;
    m0 = (wgid / nby) * 128;
    n0 = (wgid % nby) * 128;
  } else {
    m0 = blockIdx.x * 128;
    n0 = blockIdx.y * 128;
  }
  const int wr = wave >> 1, wc = wave & 1;

  f32x4 acc[4][4];
#pragma unroll
  for (int i = 0; i < 4; ++i)
#pragma unroll
    for (int j = 0; j < 4; ++j) acc[i][j] = (f32x4){0.f, 0.f, 0.f, 0.f};

  const int lrow = lane & 15;
  const int lkhi = lane >> 4;

  for (int kt = 0; kt < KD; kt += 32) {
    __syncthreads();
#pragma unroll
    for (int j = 0; j < 2; ++j) {
      int flat = tid * 16 + j * 4096;
      int row = flat >> 6;
      int cc = (flat >> 4) & 3;
      const unsigned short* src;
      if (GATHER) {
        int m = m0 + row; if (m >= M) m = 0;
        int t = m / B, b = m - t * B;
        const unsigned short* rowsrc =
            (t == 0) ? start_bf : (table_bf + (size_t)seq[b * L + t - 1] * KD);
        src = rowsrc + kt + cc * 8;
      } else {
        int m = m0 + row; if (m >= M) m = 0;
        src = A + (size_t)m * KD + kt + cc * 8;
      }
      *(int4*)((char*)a_s + flat) = *(const int4*)src;
    }
#pragma unroll
    for (int j = 0; j < 2; ++j) {
      int flat = tid * 16 + j * 4096;
      int row = flat >> 6;
      int cc = (flat >> 4) & 3;
      const unsigned short* src = W + (size_t)(n0 + row) * KD + kt + cc * 8;
      *(int4*)((char*)b_s + flat) = *(const int4*)src;
    }
    __syncthreads();

    s16x8 af[4], wf[4];
#pragma unroll
    for (int i = 0; i < 4; ++i) {
      int arow = wr * 64 + i * 16 + lrow;
      af[i] = *(const s16x8*)((const char*)a_s + arow * 64 + lkhi * 16);
      int brow = wc * 64 + i * 16 + lrow;
      wf[i] = *(const s16x8*)((const char*)b_s + brow * 64 + lkhi * 16);
    }
#pragma unroll
    for (int i = 0; i < 4; ++i)
#pragma unroll
      for (int j = 0; j < 4; ++j)
        acc[i][j] = __builtin_amdgcn_mfma_f32_16x16x32_bf16(af[i], wf[j],
                                                            acc[i][j], 0, 0, 0);
  }

#pragma unroll
  for (int i = 0; i < 4; ++i) {
#pragma unroll
    for (int r = 0; r < 4; ++r) {
      int m = m0 + wr * 64 + i * 16 + (lane >> 4) * 4 + r;
      if (m >= M) continue;
      size_t rowoff;
      if (OUTMODE == 0) {
        rowoff = (size_t)m * (size_t)Ndim;
      } else {
        int t = m / B, b = m - t * B;
        rowoff = ((size_t)b * T + t) * (size_t)Ndim;
      }
#pragma unroll
      for (int j = 0; j < 4; ++j) {
        int n = n0 + wc * 64 + j * 16 + (lane & 15);
        C[rowoff + n] = acc[i][j][r] + bias[n];
      }
    }
  }
}

// ---------------------------------------------------------------------------
// Per-step pipelined GRU kernel, 16 channels/block (math validated in R14).
// Blocks [0,NB): layer0 step t. Blocks [NB,2NB): layer1 step t-1 with
// on-the-fly x-projection. Normal cached loads; kernel boundary = barrier.
__global__ __launch_bounds__(512)
void gru_pipe16(int t, const float* __restrict__ xp0,
                const unsigned short* __restrict__ wpk0_hi,
                const unsigned short* __restrict__ wpk0_lo,
                const float* __restrict__ b_hh0,
                const unsigned short* __restrict__ wpk1_hi,
                const unsigned short* __restrict__ wpk1_lo,
                const unsigned short* __restrict__ wih1pk,
                const float* __restrict__ b_ih1,
                const float* __restrict__ b_hh1,
                const unsigned short* __restrict__ h0hi,
                const unsigned short* __restrict__ h0lo,
                const float* __restrict__ h0f,
                unsigned short* __restrict__ ys0_bf,
                unsigned short* __restrict__ lo0a, unsigned short* __restrict__ lo0b,
                float* __restrict__ h0f32,
                unsigned short* __restrict__ ys1_bf,
                unsigned short* __restrict__ lo1a, unsigned short* __restrict__ lo1b,
                float* __restrict__ h1f32) {
  __shared__ float cp[8][48][48];   // 73728 B
  const int tid = threadIdx.x;
  const bool is1 = blockIdx.x >= NB;
  const int nb = is1 ? (int)blockIdx.x - NB : (int)blockIdx.x;
  const int c0 = nb * 16;
  const int lane = tid & 63, wave = tid >> 6;   // 8 waves, K-eighth each
  const int lrow = lane & 15, lkhi = lane >> 4;

  int s = is1 ? t - 1 : t;
  if (is1 ? (s < 0) : (s >= T)) return;

  // weight row base for this lane's n-col (c = lrow) in the 8ch-packed layout
  const size_t wbase = ((size_t)(2 * nb + (lrow >> 3)) * 32 + (lrow & 7)) * KD;
  const unsigned short* whi = is1 ? wpk1_hi : wpk0_hi;
  const unsigned short* wlo = is1 ? wpk1_lo : wpk0_lo;
  const float* bhh = is1 ? b_hh1 : b_hh0;

  const unsigned short *Shi, *Slo, *Xhi = nullptr;
  const float *hold, *xp_t = nullptr;
  float* hnew_p;
  unsigned short *yhi, *ylo;
  if (!is1) {
    Shi = (s == 0) ? h0hi : ys0_bf + (size_t)(s - 1) * B * KD;
    Slo = (s == 0) ? h0lo : (((s - 1) & 1) ? lo0b : lo0a);
    hold = (s == 0) ? h0f : h0f32;
    hnew_p = h0f32;
    yhi = ys0_bf + (size_t)s * B * KD;
    ylo = (s & 1) ? lo0b : lo0a;
    xp_t = xp0 + (size_t)s * B * G3;
  } else {
    Shi = (s == 0) ? h0hi : ys1_bf + (size_t)(s - 1) * B * KD;
    Slo = (s == 0) ? h0lo : (((s - 1) & 1) ? lo1b : lo1a);
    hold = (s == 0) ? h0f : h1f32;
    hnew_p = h1f32;
    yhi = ys1_bf + (size_t)s * B * KD;
    ylo = (s & 1) ? lo1b : lo1a;
    Xhi = ys0_bf + (size_t)s * B * KD;
  }

  f32x4 acch[3][3], accx[3][3];
#pragma unroll
  for (int mt = 0; mt < 3; ++mt)
#pragma unroll
    for (int g = 0; g < 3; ++g) {
      acch[mt][g] = (f32x4){0.f, 0.f, 0.f, 0.f};
      accx[mt][g] = (f32x4){0.f, 0.f, 0.f, 0.f};
    }

#pragma unroll
  for (int ks = 0; ks < 4; ++ks) {
    int k0 = wave * 128 + ks * 32 + lkhi * 8;
    s16x8 ah[3], al[3], xh[3];
#pragma unroll
    for (int mt = 0; mt < 3; ++mt) {
      size_t hoff = (size_t)(mt * 16 + lrow) * KD + k0;
      ah[mt] = *(const s16x8*)(Shi + hoff);
      al[mt] = *(const s16x8*)(Slo + hoff);
      if (is1) xh[mt] = *(const s16x8*)(Xhi + hoff);
    }
    s16x8 bh[3], bl[3], wx[3];
#pragma unroll
    for (int g = 0; g < 3; ++g) {
      size_t off = wbase + (size_t)g * 8 * KD + k0;
      bh[g] = *(const s16x8*)(whi + off);
      bl[g] = *(const s16x8*)(wlo + off);
      if (is1) wx[g] = *(const s16x8*)(wih1pk + off);
    }
#pragma unroll
    for (int mt = 0; mt < 3; ++mt)
#pragma unroll
      for (int g = 0; g < 3; ++g) {
        acch[mt][g] = __builtin_amdgcn_mfma_f32_16x16x32_bf16(ah[mt], bh[g], acch[mt][g], 0, 0, 0);
        acch[mt][g] = __builtin_amdgcn_mfma_f32_16x16x32_bf16(al[mt], bh[g], acch[mt][g], 0, 0, 0);
        acch[mt][g] = __builtin_amdgcn_mfma_f32_16x16x32_bf16(ah[mt], bl[g], acch[mt][g], 0, 0, 0);
        if (is1)
          accx[mt][g] = __builtin_amdgcn_mfma_f32_16x16x32_bf16(xh[mt], wx[g], accx[mt][g], 0, 0, 0);
      }
  }

  // phase 1: h partials
#pragma unroll
  for (int mt = 0; mt < 3; ++mt)
#pragma unroll
    for (int g = 0; g < 3; ++g)
#pragma unroll
      for (int r = 0; r < 4; ++r)
        cp[wave][mt * 16 + (lane >> 4) * 4 + r][g * 16 + (lane & 15)] = acch[mt][g][r];
  __syncthreads();
  float ph[2][3];
#pragma unroll
  for (int i = 0; i < 2; ++i) {
    int p = tid + i * 512;
    if (p < 768) {
      int b = p >> 4, c = p & 15;
      float s0 = 0.f, s1 = 0.f, s2 = 0.f;
#pragma unroll
      for (int w = 0; w < 8; ++w) {
        s0 += cp[w][b][c];
        s1 += cp[w][b][16 + c];
        s2 += cp[w][b][32 + c];
      }
      ph[i][0] = s0; ph[i][1] = s1; ph[i][2] = s2;
    }
  }
  // phase 2 (layer1 only): x partials through the same cp buffer
  float px[2][3];
  if (is1) {
    __syncthreads();
#pragma unroll
    for (int mt = 0; mt < 3; ++mt)
#pragma unroll
      for (int g = 0; g < 3; ++g)
#pragma unroll
        for (int r = 0; r < 4; ++r)
          cp[wave][mt * 16 + (lane >> 4) * 4 + r][g * 16 + (lane & 15)] = accx[mt][g][r];
    __syncthreads();
#pragma unroll
    for (int i = 0; i < 2; ++i) {
      int p = tid + i * 512;
      if (p < 768) {
        int b = p >> 4, c = p & 15;
        float s0 = 0.f, s1 = 0.f, s2 = 0.f;
#pragma unroll
        for (int w = 0; w < 8; ++w) {
          s0 += cp[w][b][c];
          s1 += cp[w][b][16 + c];
          s2 += cp[w][b][32 + c];
        }
        px[i][0] = s0; px[i][1] = s1; px[i][2] = s2;
      }
    }
  }

  // gate + state update: 768 (b,c) pairs
#pragma unroll
  for (int i = 0; i < 2; ++i) {
    int p = tid + i * 512;
    if (p >= 768) break;
    int b = p >> 4, c = p & 15;
    int gc = c0 + c;
    float xr, xz, xn;
    if (is1) {
      xr = px[i][0] + b_ih1[gc];
      xz = px[i][1] + b_ih1[KD + gc];
      xn = px[i][2] + b_ih1[2 * KD + gc];
    } else {
      const float* xrow = xp_t + (size_t)b * G3;
      xr = xrow[gc]; xz = xrow[KD + gc]; xn = xrow[2 * KD + gc];
    }
    float hr = ph[i][0] + bhh[gc];
    float hz = ph[i][1] + bhh[KD + gc];
    float hn = ph[i][2] + bhh[2 * KD + gc];
    float r_ = 1.f / (1.f + expf(-(xr + hr)));
    float z_ = 1.f / (1.f + expf(-(xz + hz)));
    float n_ = tanhf(xn + r_ * hn);
    float hv = hold[(size_t)b * KD + gc];
    float hnew = (1.f - z_) * n_ + z_ * hv;
    hnew_p[(size_t)b * KD + gc] = hnew;
    unsigned short hi = f2bf(hnew);
    yhi[(size_t)b * KD + gc] = hi;
    ylo[(size_t)b * KD + gc] = f2bf(hnew - bf2f(hi));
  }
}

// ---------------------------------------------------------------------------
__global__ __launch_bounds__(256)
void softmax_mask(float* __restrict__ out, const int* __restrict__ seq) {
  const int t = blockIdx.x, b = blockIdx.y;
  float* row = out + ((size_t)b * T + t) * V;
  __shared__ unsigned bits[V / 32];
  __shared__ float red[4];
  const int tid = threadIdx.x;
  const bool masked = (t < L - 1);
  if (masked) {
    bits[tid] = 0u;
    __syncthreads();
    int rem = L - t;
    if (tid < rem) {
      int id = seq[b * L + t + tid];
      atomicOr(&bits[id >> 5], 1u << (id & 31));
    }
  }
  __syncthreads();

  float4 x[8];
  float mx = -3.0e38f;
#pragma unroll
  for (int j = 0; j < 8; ++j) {
    float4 v = ((const float4*)row)[j * 256 + tid];
    if (masked) {
      int vb = (j * 256 + tid) * 4;
      unsigned wrd = bits[vb >> 5];
      int sh = vb & 31;
      if (!((wrd >> (sh + 0)) & 1u)) v.x = -1.0e30f;
      if (!((wrd >> (sh + 1)) & 1u)) v.y = -1.0e30f;
      if (!((wrd >> (sh + 2)) & 1u)) v.z = -1.0e30f;
      if (!((wrd >> (sh + 3)) & 1u)) v.w = -1.0e30f;
    }
    x[j] = v;
    mx = fmaxf(mx, fmaxf(fmaxf(v.x, v.y), fmaxf(v.z, v.w)));
  }
#pragma unroll
  for (int off = 32; off > 0; off >>= 1) mx = fmaxf(mx, __shfl_xor(mx, off));
  int wv = tid >> 6;
  if ((tid & 63) == 0) red[wv] = mx;
  __syncthreads();
  mx = fmaxf(fmaxf(red[0], red[1]), fmaxf(red[2], red[3]));

  float s = 0.f;
#pragma unroll
  for (int j = 0; j < 8; ++j) {
    x[j].x = expf(x[j].x - mx); x[j].y = expf(x[j].y - mx);
    x[j].z = expf(x[j].z - mx); x[j].w = expf(x[j].w - mx);
    s += x[j].x + x[j].y + x[j].z + x[j].w;
  }
#pragma unroll
  for (int off = 32; off > 0; off >>= 1) s += __shfl_xor(s, off);
  __syncthreads();
  if ((tid & 63) == 0) red[wv] = s;
  __syncthreads();
  s = red[0] + red[1] + red[2] + red[3];
  float inv = 1.f / s;
#pragma unroll
  for (int j = 0; j < 8; ++j) {
    float4 v = make_float4(x[j].x * inv, x[j].y * inv, x[j].z * inv, x[j].w * inv);
    ((float4*)row)[j * 256 + tid] = v;
  }
}

// ---------------------------------------------------------------------------
extern "C" void kernel_launch(void* const* d_in, const int* in_sizes, int n_in,
                              void* d_out, int out_size, void* d_ws, size_t ws_size,
                              hipStream_t stream) {
  const float* event_table = (const float*)d_in[0];
  const float* user_table  = (const float*)d_in[1];
  const float* startv      = (const float*)d_in[2];
  const float* w_ih0 = (const float*)d_in[3];
  const float* w_hh0 = (const float*)d_in[4];
  const float* b_ih0 = (const float*)d_in[5];
  const float* b_hh0 = (const float*)d_in[6];
  const float* w_ih1 = (const float*)d_in[7];
  const float* w_hh1 = (const float*)d_in[8];
  const float* b_ih1 = (const float*)d_in[9];
  const float* b_hh1 = (const float*)d_in[10];
  const float* lin_w = (const float*)d_in[11];
  const float* lin_b = (const float*)d_in[12];
  const int*   ids   = (const int*)d_in[13];
  const int*   seq   = (const int*)d_in[14];
  float* out = (float*)d_out;

  // workspace layout (~235 MB)
  float* xp0  = (float*)d_ws;                           // M*G3 f32
  float* h0f  = xp0 + (size_t)M * G3;                   // B*KD
  float* h0f32 = h0f + (size_t)B * KD;                  // B*KD (layer0 state)
  float* h1f32 = h0f32 + (size_t)B * KD;                // B*KD (layer1 state)
  unsigned short* ut_bf    = (unsigned short*)(h1f32 + (size_t)B * KD);
  unsigned short* start_bf = ut_bf    + (size_t)V * KD;
  unsigned short* wih0_bf  = start_bf + KD;
  unsigned short* linw_bf  = wih0_bf  + (size_t)G3 * KD;
  unsigned short* ys0_bf   = linw_bf  + (size_t)V * KD;
  unsigned short* ys1_bf   = ys0_bf   + (size_t)M * KD;
  unsigned short* h0hi     = ys1_bf   + (size_t)M * KD;
  unsigned short* h0lo     = h0hi + (size_t)B * KD;
  unsigned short* lo0a     = h0lo + (size_t)B * KD;
  unsigned short* lo0b     = lo0a + (size_t)B * KD;
  unsigned short* lo1a     = lo0b + (size_t)B * KD;
  unsigned short* lo1b     = lo1a + (size_t)B * KD;
  unsigned short* wpk0_hi  = lo1b + (size_t)B * KD;
  unsigned short* wpk0_lo  = wpk0_hi + (size_t)SB * 32 * KD;
  unsigned short* wpk1_hi  = wpk0_lo + (size_t)SB * 32 * KD;
  unsigned short* wpk1_lo  = wpk1_hi + (size_t)SB * 32 * KD;
  unsigned short* wih1pk   = wpk1_lo + (size_t)SB * 32 * KD;

  init_h0<<<dim3(B), 256, 0, stream>>>(event_table, ids, h0f, h0hi, h0lo);

  auto cvt = [&](const float* src, unsigned short* dst, long long n) {
    int blocks = (int)((n + 2047) / 2048);
    cvt_bf16<<<dim3(blocks), 256, 0, stream>>>(src, dst, n);
  };
  cvt(user_table, ut_bf,    (long long)V * KD);
  cvt(startv,     start_bf, KD);
  cvt(w_ih0,      wih0_bf,  (long long)G3 * KD);
  cvt(lin_w,      linw_bf,  (long long)V * KD);

  repack_whh<<<dim3(SB * 32 * KD / 2048), 256, 0, stream>>>(w_hh0, wpk0_hi, wpk0_lo);
  repack_whh<<<dim3(SB * 32 * KD / 2048), 256, 0, stream>>>(w_hh1, wpk1_hi, wpk1_lo);
  repack_w_single<<<dim3(SB * 32 * KD / 2048), 256, 0, stream>>>(w_ih1, wih1pk);

  // layer 0 input projection (gather from bf16 tables), validated 2D grid
  gemm_bf16<1, 0, 0><<<dim3((M + 127) / 128, G3 / 128), 256, 0, stream>>>(
      nullptr, wih0_bf, b_ih0, xp0, G3, seq, start_bf, ut_bf);

  // pipelined two-layer scan: T+1 launches, 16 channels per block
  for (int t = 0; t <= T; ++t) {
    gru_pipe16<<<dim3(2 * NB), dim3(512), 0, stream>>>(
        t, xp0, wpk0_hi, wpk0_lo, b_hh0, wpk1_hi, wpk1_lo, wih1pk, b_ih1, b_hh1,
        h0hi, h0lo, h0f, ys0_bf, lo0a, lo0b, h0f32, ys1_bf, lo1a, lo1b, h1f32);
  }

  // logits into d_out at [b][t][v], 1D XCD-swizzled grid
  gemm_bf16<0, 1, 1><<<dim3(((M + 127) / 128) * (V / 128)), 256, 0, stream>>>(
      ys1_bf, linw_bf, lin_b, out, V, nullptr, nullptr, nullptr);

  // masked softmax in place
  softmax_mask<<<dim3(T, B), 256, 0, stream>>>(out, seq);
}

// Round 17
// 3987.681 us; speedup vs baseline: 2.0608x; 1.1889x over previous
//
#include <hip/hip_runtime.h>
#include <cstddef>
#include <cstdint>

constexpr int B  = 48;
constexpr int L  = 192;
constexpr int T  = 193;    // L + 1
constexpr int KD = 1024;   // I == H
constexpr int G3 = 3072;   // 3*H
constexpr int V  = 8192;
constexpr int M  = T * B;  // 9264
constexpr int SB = 128;    // scan blocks per layer: 8 h-channels each

typedef float f32x4 __attribute__((ext_vector_type(4)));
typedef short s16x8 __attribute__((ext_vector_type(8)));
typedef unsigned short u16x8 __attribute__((ext_vector_type(8)));

__device__ inline unsigned short f2bf(float f) {
  unsigned u = __builtin_bit_cast(unsigned, f);
  u += 0x7fffu + ((u >> 16) & 1u);   // round-to-nearest-even
  return (unsigned short)(u >> 16);
}
__device__ inline float bf2f(unsigned short h) {
  return __builtin_bit_cast(float, (unsigned)h << 16);
}

// ---------------------------------------------------------------------------
__global__ __launch_bounds__(256)
void init_h0(const float* __restrict__ et, const int* __restrict__ ids,
             float* __restrict__ h0f, unsigned short* __restrict__ h0hi,
             unsigned short* __restrict__ h0lo) {
  int b = blockIdx.x;
  int id = ids[b];
  float4 v = ((const float4*)(et + (size_t)id * KD))[threadIdx.x];
  ((float4*)(h0f + (size_t)b * KD))[threadIdx.x] = v;
  int base = b * KD + threadIdx.x * 4;
  float vv[4] = {v.x, v.y, v.z, v.w};
#pragma unroll
  for (int j = 0; j < 4; ++j) {
    unsigned short hi = f2bf(vv[j]);
    h0hi[base + j] = hi;
    h0lo[base + j] = f2bf(vv[j] - bf2f(hi));
  }
}

// fp32 -> bf16 (raw bits), 8 elems/thread
__global__ __launch_bounds__(256)
void cvt_bf16(const float* __restrict__ in, unsigned short* __restrict__ out,
              long long n) {
  long long i = ((long long)blockIdx.x * 256 + threadIdx.x) * 8;
  if (i + 8 > n) return;
  float4 v0 = *(const float4*)(in + i);
  float4 v1 = *(const float4*)(in + i + 4);
  u16x8 o;
  o[0] = f2bf(v0.x); o[1] = f2bf(v0.y); o[2] = f2bf(v0.z); o[3] = f2bf(v0.w);
  o[4] = f2bf(v1.x); o[5] = f2bf(v1.y); o[6] = f2bf(v1.z); o[7] = f2bf(v1.w);
  *(u16x8*)(out + i) = o;
}

// ---------------------------------------------------------------------------
// Repack [3*KD, KD] fp32 weights -> per-8ch-block split-bf16 [SB][32][KD].
__global__ __launch_bounds__(256)
void repack_whh(const float* __restrict__ w_hh, unsigned short* __restrict__ hi,
                unsigned short* __restrict__ lo) {
  long long idx = ((long long)blockIdx.x * 256 + threadIdx.x) * 8;
  if (idx >= (long long)SB * 32 * KD) return;
  int k  = (int)(idx & (KD - 1));
  int rr = (int)(idx >> 10);
  int r = rr & 31, bid = rr >> 5;
  u16x8 h8 = (u16x8)0, l8 = (u16x8)0;
  if (r < 24) {
    int g = r >> 3, c = bid * 8 + (r & 7);
    const float* src = w_hh + ((size_t)(g * KD + c)) * KD + k;
    float4 v0 = *(const float4*)src, v1 = *(const float4*)(src + 4);
    float vv[8] = {v0.x, v0.y, v0.z, v0.w, v1.x, v1.y, v1.z, v1.w};
#pragma unroll
    for (int j = 0; j < 8; ++j) {
      unsigned short h = f2bf(vv[j]);
      h8[j] = h;
      l8[j] = f2bf(vv[j] - bf2f(h));
    }
  }
  *(u16x8*)(hi + idx) = h8;
  *(u16x8*)(lo + idx) = l8;
}

// Same packing, single bf16 (w_ih1 for the on-the-fly x-projection).
__global__ __launch_bounds__(256)
void repack_w_single(const float* __restrict__ w, unsigned short* __restrict__ pk) {
  long long idx = ((long long)blockIdx.x * 256 + threadIdx.x) * 8;
  if (idx >= (long long)SB * 32 * KD) return;
  int k  = (int)(idx & (KD - 1));
  int rr = (int)(idx >> 10);
  int r = rr & 31, bid = rr >> 5;
  u16x8 h8 = (u16x8)0;
  if (r < 24) {
    int g = r >> 3, c = bid * 8 + (r & 7);
    const float* src = w + ((size_t)(g * KD + c)) * KD + k;
    float4 v0 = *(const float4*)src, v1 = *(const float4*)(src + 4);
    float vv[8] = {v0.x, v0.y, v0.z, v0.w, v1.x, v1.y, v1.z, v1.w};
#pragma unroll
    for (int j = 0; j < 8; ++j) h8[j] = f2bf(vv[j]);
  }
  *(u16x8*)(pk + idx) = h8;
}

// ---------------------------------------------------------------------------
// bf16 MFMA GEMM (validated R2/R7): C[m,n] = sum_k A[m,k]*W[n,k] + bias[n].
// SWZ=1: 1D grid with bijective XCD-chunk swizzle (validated R16: -11% FETCH).
template<int GATHER, int OUTMODE, int SWZ>
__global__ __launch_bounds__(256)
void gemm_bf16(const unsigned short* __restrict__ A,
               const unsigned short* __restrict__ W,
               const float* __restrict__ bias, float* __restrict__ C, int Ndim,
               const int* __restrict__ seq,
               const unsigned short* __restrict__ start_bf,
               const unsigned short* __restrict__ table_bf) {
  __shared__ __align__(16) unsigned short a_s[128 * 32];
  __shared__ __align__(16) unsigned short b_s[128 * 32];
  const int tid  = threadIdx.x;
  const int lane = tid & 63;
  const int wave = tid >> 6;
  int m0, n0;
  if (SWZ) {
    const int nwg = gridDim.x;
    const int q = nwg >> 3, r8 = nwg & 7;
    const int xcd = blockIdx.x & 7, oidx = blockIdx.x >> 3;
    const int wgid = (xcd < r8 ? xcd * (q + 1) : r8 * (q + 1) + (xcd - r8) * q) + oidx;
    const int nby = Ndim >> 7;
    m0 = (wgid / nby) * 128;
    n0 = (wgid % nby) * 128;
  } else {
    m0 = blockIdx.x * 128;
    n0 = blockIdx.y * 128;
  }
  const int wr = wave >> 1, wc = wave & 1;

  f32x4 acc[4][4];
#pragma unroll
  for (int i = 0; i < 4; ++i)
#pragma unroll
    for (int j = 0; j < 4; ++j) acc[i][j] = (f32x4){0.f, 0.f, 0.f, 0.f};

  const int lrow = lane & 15;
  const int lkhi = lane >> 4;

  for (int kt = 0; kt < KD; kt += 32) {
    __syncthreads();
#pragma unroll
    for (int j = 0; j < 2; ++j) {
      int flat = tid * 16 + j * 4096;
      int row = flat >> 6;
      int cc = (flat >> 4) & 3;
      const unsigned short* src;
      if (GATHER) {
        int m = m0 + row; if (m >= M) m = 0;
        int t = m / B, b = m - t * B;
        const unsigned short* rowsrc =
            (t == 0) ? start_bf : (table_bf + (size_t)seq[b * L + t - 1] * KD);
        src = rowsrc + kt + cc * 8;
      } else {
        int m = m0 + row; if (m >= M) m = 0;
        src = A + (size_t)m * KD + kt + cc * 8;
      }
      *(int4*)((char*)a_s + flat) = *(const int4*)src;
    }
#pragma unroll
    for (int j = 0; j < 2; ++j) {
      int flat = tid * 16 + j * 4096;
      int row = flat >> 6;
      int cc = (flat >> 4) & 3;
      const unsigned short* src = W + (size_t)(n0 + row) * KD + kt + cc * 8;
      *(int4*)((char*)b_s + flat) = *(const int4*)src;
    }
    __syncthreads();

    s16x8 af[4], wf[4];
#pragma unroll
    for (int i = 0; i < 4; ++i) {
      int arow = wr * 64 + i * 16 + lrow;
      af[i] = *(const s16x8*)((const char*)a_s + arow * 64 + lkhi * 16);
      int brow = wc * 64 + i * 16 + lrow;
      wf[i] = *(const s16x8*)((const char*)b_s + brow * 64 + lkhi * 16);
    }
#pragma unroll
    for (int i = 0; i < 4; ++i)
#pragma unroll
      for (int j = 0; j < 4; ++j)
        acc[i][j] = __builtin_amdgcn_mfma_f32_16x16x32_bf16(af[i], wf[j],
                                                            acc[i][j], 0, 0, 0);
  }

#pragma unroll
  for (int i = 0; i < 4; ++i) {
#pragma unroll
    for (int r = 0; r < 4; ++r) {
      int m = m0 + wr * 64 + i * 16 + (lane >> 4) * 4 + r;
      if (m >= M) continue;
      size_t rowoff;
      if (OUTMODE == 0) {
        rowoff = (size_t)m * (size_t)Ndim;
      } else {
        int t = m / B, b = m - t * B;
        rowoff = ((size_t)b * T + t) * (size_t)Ndim;
      }
#pragma unroll
      for (int j = 0; j < 4; ++j) {
        int n = n0 + wc * 64 + j * 16 + (lane & 15);
        C[rowoff + n] = acc[i][j][r] + bias[n];
      }
    }
  }
}

// ---------------------------------------------------------------------------
// Per-step pipelined GRU kernel: 8 channels/block, 256 blocks (all CUs),
// 512 threads = 8 waves splitting K 8-ways for latency hiding (R16 lesson:
// scan is per-CU load-latency bound, not BW bound).
// Blocks [0,SB): layer0 step t. Blocks [SB,2SB): layer1 step t-1 with
// on-the-fly x-projection.
__global__ __launch_bounds__(512)
void gru_pipe(int t, const float* __restrict__ xp0,
              const unsigned short* __restrict__ wpk0_hi,
              const unsigned short* __restrict__ wpk0_lo,
              const float* __restrict__ b_hh0,
              const unsigned short* __restrict__ wpk1_hi,
              const unsigned short* __restrict__ wpk1_lo,
              const unsigned short* __restrict__ wih1pk,
              const float* __restrict__ b_ih1,
              const float* __restrict__ b_hh1,
              const unsigned short* __restrict__ h0hi,
              const unsigned short* __restrict__ h0lo,
              const float* __restrict__ h0f,
              unsigned short* __restrict__ ys0_bf,
              unsigned short* __restrict__ lo0a, unsigned short* __restrict__ lo0b,
              float* __restrict__ h0f32,
              unsigned short* __restrict__ ys1_bf,
              unsigned short* __restrict__ lo1a, unsigned short* __restrict__ lo1b,
              float* __restrict__ h1f32) {
  __shared__ float cp[8][48 * 33];   // 50688 B
  const int tid = threadIdx.x;
  const bool is1 = blockIdx.x >= SB;
  const int bid = is1 ? (int)blockIdx.x - SB : (int)blockIdx.x;
  const int c0 = bid * 8;
  const int lane = tid & 63, wave = tid >> 6;   // 8 waves, K-eighth each
  const int lrow = lane & 15, lkhi = lane >> 4;

  int s = is1 ? t - 1 : t;
  if (is1 ? (s < 0) : (s >= T)) return;

  const unsigned short* wb_hi = (is1 ? wpk1_hi : wpk0_hi) + (size_t)bid * 32 * KD;
  const unsigned short* wb_lo = (is1 ? wpk1_lo : wpk0_lo) + (size_t)bid * 32 * KD;
  const unsigned short* wb_wx = wih1pk + (size_t)bid * 32 * KD;
  const float* bhh = is1 ? b_hh1 : b_hh0;

  const unsigned short *Shi, *Slo, *Xhi = nullptr;
  const float *hold, *xp_t = nullptr;
  float* hnew_p;
  unsigned short *yhi, *ylo;
  if (!is1) {
    Shi = (s == 0) ? h0hi : ys0_bf + (size_t)(s - 1) * B * KD;
    Slo = (s == 0) ? h0lo : (((s - 1) & 1) ? lo0b : lo0a);
    hold = (s == 0) ? h0f : h0f32;
    hnew_p = h0f32;
    yhi = ys0_bf + (size_t)s * B * KD;
    ylo = (s & 1) ? lo0b : lo0a;
    xp_t = xp0 + (size_t)s * B * G3;
  } else {
    Shi = (s == 0) ? h0hi : ys1_bf + (size_t)(s - 1) * B * KD;
    Slo = (s == 0) ? h0lo : (((s - 1) & 1) ? lo1b : lo1a);
    hold = (s == 0) ? h0f : h1f32;
    hnew_p = h1f32;
    yhi = ys1_bf + (size_t)s * B * KD;
    ylo = (s & 1) ? lo1b : lo1a;
    Xhi = ys0_bf + (size_t)s * B * KD;
  }

  // w-rows for the two 16-row n-tiles (24 real rows, clamp pad)
  int rB0 = lrow;
  int rB1 = 16 + lrow; if (rB1 > 23) rB1 = 23;

  f32x4 acc_h[3][2], acc_x[3][2];
#pragma unroll
  for (int mt = 0; mt < 3; ++mt)
#pragma unroll
    for (int nt = 0; nt < 2; ++nt) {
      acc_h[mt][nt] = (f32x4){0.f, 0.f, 0.f, 0.f};
      acc_x[mt][nt] = (f32x4){0.f, 0.f, 0.f, 0.f};
    }

#pragma unroll
  for (int ks = 0; ks < 4; ++ks) {
    int k0 = wave * 128 + ks * 32 + lkhi * 8;
    s16x8 ah[3], al[3], xh[3];
#pragma unroll
    for (int mt = 0; mt < 3; ++mt) {
      size_t hoff = (size_t)(mt * 16 + lrow) * KD + k0;
      ah[mt] = *(const s16x8*)(Shi + hoff);
      al[mt] = *(const s16x8*)(Slo + hoff);
      if (is1) xh[mt] = *(const s16x8*)(Xhi + hoff);
    }
    s16x8 bh[2], bl[2], wx[2];
    {
      size_t o0 = (size_t)rB0 * KD + k0, o1 = (size_t)rB1 * KD + k0;
      bh[0] = *(const s16x8*)(wb_hi + o0); bh[1] = *(const s16x8*)(wb_hi + o1);
      bl[0] = *(const s16x8*)(wb_lo + o0); bl[1] = *(const s16x8*)(wb_lo + o1);
      if (is1) { wx[0] = *(const s16x8*)(wb_wx + o0); wx[1] = *(const s16x8*)(wb_wx + o1); }
    }
#pragma unroll
    for (int mt = 0; mt < 3; ++mt)
#pragma unroll
      for (int nt = 0; nt < 2; ++nt) {
        acc_h[mt][nt] = __builtin_amdgcn_mfma_f32_16x16x32_bf16(ah[mt], bh[nt], acc_h[mt][nt], 0, 0, 0);
        acc_h[mt][nt] = __builtin_amdgcn_mfma_f32_16x16x32_bf16(al[mt], bh[nt], acc_h[mt][nt], 0, 0, 0);
        acc_h[mt][nt] = __builtin_amdgcn_mfma_f32_16x16x32_bf16(ah[mt], bl[nt], acc_h[mt][nt], 0, 0, 0);
        if (is1)
          acc_x[mt][nt] = __builtin_amdgcn_mfma_f32_16x16x32_bf16(xh[mt], wx[nt], acc_x[mt][nt], 0, 0, 0);
      }
  }

  // phase 1: h partials -> cp[wave]
#pragma unroll
  for (int mt = 0; mt < 3; ++mt)
#pragma unroll
    for (int nt = 0; nt < 2; ++nt)
#pragma unroll
      for (int r = 0; r < 4; ++r) {
        int row = mt * 16 + (lane >> 4) * 4 + r;
        cp[wave][row * 33 + nt * 16 + (lane & 15)] = acc_h[mt][nt][r];
      }
  __syncthreads();
  float ph[3] = {0.f, 0.f, 0.f};
  if (tid < 384) {
    int b = tid >> 3, c = tid & 7;
#pragma unroll
    for (int w = 0; w < 8; ++w) {
      ph[0] += cp[w][b * 33 + c];
      ph[1] += cp[w][b * 33 + 8 + c];
      ph[2] += cp[w][b * 33 + 16 + c];
    }
  }
  // phase 2 (layer1 only): x partials through the same cp buffer
  float px[3] = {0.f, 0.f, 0.f};
  if (is1) {
    __syncthreads();
#pragma unroll
    for (int mt = 0; mt < 3; ++mt)
#pragma unroll
      for (int nt = 0; nt < 2; ++nt)
#pragma unroll
        for (int r = 0; r < 4; ++r) {
          int row = mt * 16 + (lane >> 4) * 4 + r;
          cp[wave][row * 33 + nt * 16 + (lane & 15)] = acc_x[mt][nt][r];
        }
    __syncthreads();
    if (tid < 384) {
      int b = tid >> 3, c = tid & 7;
#pragma unroll
      for (int w = 0; w < 8; ++w) {
        px[0] += cp[w][b * 33 + c];
        px[1] += cp[w][b * 33 + 8 + c];
        px[2] += cp[w][b * 33 + 16 + c];
      }
    }
  }

  // gate + state update: 384 (b,c) pairs
  if (tid < 384) {
    int b = tid >> 3, c = tid & 7;
    int gc = c0 + c;
    float xr, xz, xn;
    if (is1) {
      xr = px[0] + b_ih1[gc];
      xz = px[1] + b_ih1[KD + gc];
      xn = px[2] + b_ih1[2 * KD + gc];
    } else {
      const float* xrow = xp_t + (size_t)b * G3;
      xr = xrow[gc]; xz = xrow[KD + gc]; xn = xrow[2 * KD + gc];
    }
    float hr = ph[0] + bhh[gc];
    float hz = ph[1] + bhh[KD + gc];
    float hn = ph[2] + bhh[2 * KD + gc];
    float r_ = 1.f / (1.f + expf(-(xr + hr)));
    float z_ = 1.f / (1.f + expf(-(xz + hz)));
    float n_ = tanhf(xn + r_ * hn);
    float hv = hold[(size_t)b * KD + gc];
    float hnew = (1.f - z_) * n_ + z_ * hv;
    hnew_p[(size_t)b * KD + gc] = hnew;
    unsigned short hi = f2bf(hnew);
    yhi[(size_t)b * KD + gc] = hi;
    ylo[(size_t)b * KD + gc] = f2bf(hnew - bf2f(hi));
  }
}

// ---------------------------------------------------------------------------
__global__ __launch_bounds__(256)
void softmax_mask(float* __restrict__ out, const int* __restrict__ seq) {
  const int t = blockIdx.x, b = blockIdx.y;
  float* row = out + ((size_t)b * T + t) * V;
  __shared__ unsigned bits[V / 32];
  __shared__ float red[4];
  const int tid = threadIdx.x;
  const bool masked = (t < L - 1);
  if (masked) {
    bits[tid] = 0u;
    __syncthreads();
    int rem = L - t;
    if (tid < rem) {
      int id = seq[b * L + t + tid];
      atomicOr(&bits[id >> 5], 1u << (id & 31));
    }
  }
  __syncthreads();

  float4 x[8];
  float mx = -3.0e38f;
#pragma unroll
  for (int j = 0; j < 8; ++j) {
    float4 v = ((const float4*)row)[j * 256 + tid];
    if (masked) {
      int vb = (j * 256 + tid) * 4;
      unsigned wrd = bits[vb >> 5];
      int sh = vb & 31;
      if (!((wrd >> (sh + 0)) & 1u)) v.x = -1.0e30f;
      if (!((wrd >> (sh + 1)) & 1u)) v.y = -1.0e30f;
      if (!((wrd >> (sh + 2)) & 1u)) v.z = -1.0e30f;
      if (!((wrd >> (sh + 3)) & 1u)) v.w = -1.0e30f;
    }
    x[j] = v;
    mx = fmaxf(mx, fmaxf(fmaxf(v.x, v.y), fmaxf(v.z, v.w)));
  }
#pragma unroll
  for (int off = 32; off > 0; off >>= 1) mx = fmaxf(mx, __shfl_xor(mx, off));
  int wv = tid >> 6;
  if ((tid & 63) == 0) red[wv] = mx;
  __syncthreads();
  mx = fmaxf(fmaxf(red[0], red[1]), fmaxf(red[2], red[3]));

  float s = 0.f;
#pragma unroll
  for (int j = 0; j < 8; ++j) {
    x[j].x = expf(x[j].x - mx); x[j].y = expf(x[j].y - mx);
    x[j].z = expf(x[j].z - mx); x[j].w = expf(x[j].w - mx);
    s += x[j].x + x[j].y + x[j].z + x[j].w;
  }
#pragma unroll
  for (int off = 32; off > 0; off >>= 1) s += __shfl_xor(s, off);
  __syncthreads();
  if ((tid & 63) == 0) red[wv] = s;
  __syncthreads();
  s = red[0] + red[1] + red[2] + red[3];
  float inv = 1.f / s;
#pragma unroll
  for (int j = 0; j < 8; ++j) {
    float4 v = make_float4(x[j].x * inv, x[j].y * inv, x[j].z * inv, x[j].w * inv);
    ((float4*)row)[j * 256 + tid] = v;
  }
}

// ---------------------------------------------------------------------------
extern "C" void kernel_launch(void* const* d_in, const int* in_sizes, int n_in,
                              void* d_out, int out_size, void* d_ws, size_t ws_size,
                              hipStream_t stream) {
  const float* event_table = (const float*)d_in[0];
  const float* user_table  = (const float*)d_in[1];
  const float* startv      = (const float*)d_in[2];
  const float* w_ih0 = (const float*)d_in[3];
  const float* w_hh0 = (const float*)d_in[4];
  const float* b_ih0 = (const float*)d_in[5];
  const float* b_hh0 = (const float*)d_in[6];
  const float* w_ih1 = (const float*)d_in[7];
  const float* w_hh1 = (const float*)d_in[8];
  const float* b_ih1 = (const float*)d_in[9];
  const float* b_hh1 = (const float*)d_in[10];
  const float* lin_w = (const float*)d_in[11];
  const float* lin_b = (const float*)d_in[12];
  const int*   ids   = (const int*)d_in[13];
  const int*   seq   = (const int*)d_in[14];
  float* out = (float*)d_out;

  // workspace layout (~235 MB)
  float* xp0  = (float*)d_ws;                           // M*G3 f32
  float* h0f  = xp0 + (size_t)M * G3;                   // B*KD
  float* h0f32 = h0f + (size_t)B * KD;                  // B*KD (layer0 state)
  float* h1f32 = h0f32 + (size_t)B * KD;                // B*KD (layer1 state)
  unsigned short* ut_bf    = (unsigned short*)(h1f32 + (size_t)B * KD);
  unsigned short* start_bf = ut_bf    + (size_t)V * KD;
  unsigned short* wih0_bf  = start_bf + KD;
  unsigned short* linw_bf  = wih0_bf  + (size_t)G3 * KD;
  unsigned short* ys0_bf   = linw_bf  + (size_t)V * KD;
  unsigned short* ys1_bf   = ys0_bf   + (size_t)M * KD;
  unsigned short* h0hi     = ys1_bf   + (size_t)M * KD;
  unsigned short* h0lo     = h0hi + (size_t)B * KD;
  unsigned short* lo0a     = h0lo + (size_t)B * KD;
  unsigned short* lo0b     = lo0a + (size_t)B * KD;
  unsigned short* lo1a     = lo0b + (size_t)B * KD;
  unsigned short* lo1b     = lo1a + (size_t)B * KD;
  unsigned short* wpk0_hi  = lo1b + (size_t)B * KD;
  unsigned short* wpk0_lo  = wpk0_hi + (size_t)SB * 32 * KD;
  unsigned short* wpk1_hi  = wpk0_lo + (size_t)SB * 32 * KD;
  unsigned short* wpk1_lo  = wpk1_hi + (size_t)SB * 32 * KD;
  unsigned short* wih1pk   = wpk1_lo + (size_t)SB * 32 * KD;

  init_h0<<<dim3(B), 256, 0, stream>>>(event_table, ids, h0f, h0hi, h0lo);

  auto cvt = [&](const float* src, unsigned short* dst, long long n) {
    int blocks = (int)((n + 2047) / 2048);
    cvt_bf16<<<dim3(blocks), 256, 0, stream>>>(src, dst, n);
  };
  cvt(user_table, ut_bf,    (long long)V * KD);
  cvt(startv,     start_bf, KD);
  cvt(w_ih0,      wih0_bf,  (long long)G3 * KD);
  cvt(lin_w,      linw_bf,  (long long)V * KD);

  repack_whh<<<dim3(SB * 32 * KD / 2048), 256, 0, stream>>>(w_hh0, wpk0_hi, wpk0_lo);
  repack_whh<<<dim3(SB * 32 * KD / 2048), 256, 0, stream>>>(w_hh1, wpk1_hi, wpk1_lo);
  repack_w_single<<<dim3(SB * 32 * KD / 2048), 256, 0, stream>>>(w_ih1, wih1pk);

  // layer 0 input projection (gather from bf16 tables)
  gemm_bf16<1, 0, 0><<<dim3((M + 127) / 128, G3 / 128), 256, 0, stream>>>(
      nullptr, wih0_bf, b_ih0, xp0, G3, seq, start_bf, ut_bf);

  // pipelined two-layer scan: T+1 launches, 256 blocks x 512 threads
  for (int t = 0; t <= T; ++t) {
    gru_pipe<<<dim3(2 * SB), dim3(512), 0, stream>>>(
        t, xp0, wpk0_hi, wpk0_lo, b_hh0, wpk1_hi, wpk1_lo, wih1pk, b_ih1, b_hh1,
        h0hi, h0lo, h0f, ys0_bf, lo0a, lo0b, h0f32, ys1_bf, lo1a, lo1b, h1f32);
  }

  // logits into d_out at [b][t][v], 1D XCD-swizzled grid (validated R16)
  gemm_bf16<0, 1, 1><<<dim3(((M + 127) / 128) * (V / 128)), 256, 0, stream>>>(
      ys1_bf, linw_bf, lin_b, out, V, nullptr, nullptr, nullptr);

  // masked softmax in place
  softmax_mask<<<dim3(T, B), 256, 0, stream>>>(out, seq);
}

// Round 18
// 3455.775 us; speedup vs baseline: 2.3780x; 1.1539x over previous
//
#include <hip/hip_runtime.h>
#include <cstddef>
#include <cstdint>

constexpr int B  = 48;
constexpr int L  = 192;
constexpr int T  = 193;    // L + 1
constexpr int KD = 1024;   // I == H
constexpr int G3 = 3072;   // 3*H
constexpr int V  = 8192;
constexpr int M  = T * B;  // 9264
constexpr int SB = 128;    // scan blocks per layer: 8 h-channels each

typedef float f32x4 __attribute__((ext_vector_type(4)));
typedef short s16x8 __attribute__((ext_vector_type(8)));
typedef unsigned short u16x8 __attribute__((ext_vector_type(8)));

__device__ inline unsigned short f2bf(float f) {
  unsigned u = __builtin_bit_cast(unsigned, f);
  u += 0x7fffu + ((u >> 16) & 1u);   // round-to-nearest-even
  return (unsigned short)(u >> 16);
}
__device__ inline float bf2f(unsigned short h) {
  return __builtin_bit_cast(float, (unsigned)h << 16);
}

// ---------------------------------------------------------------------------
__global__ __launch_bounds__(256)
void init_h0(const float* __restrict__ et, const int* __restrict__ ids,
             float* __restrict__ h0f, unsigned short* __restrict__ h0hi) {
  int b = blockIdx.x;
  int id = ids[b];
  float4 v = ((const float4*)(et + (size_t)id * KD))[threadIdx.x];
  ((float4*)(h0f + (size_t)b * KD))[threadIdx.x] = v;
  int base = b * KD + threadIdx.x * 4;
  float vv[4] = {v.x, v.y, v.z, v.w};
#pragma unroll
  for (int j = 0; j < 4; ++j) h0hi[base + j] = f2bf(vv[j]);
}

// fp32 -> bf16 (raw bits), 8 elems/thread
__global__ __launch_bounds__(256)
void cvt_bf16(const float* __restrict__ in, unsigned short* __restrict__ out,
              long long n) {
  long long i = ((long long)blockIdx.x * 256 + threadIdx.x) * 8;
  if (i + 8 > n) return;
  float4 v0 = *(const float4*)(in + i);
  float4 v1 = *(const float4*)(in + i + 4);
  u16x8 o;
  o[0] = f2bf(v0.x); o[1] = f2bf(v0.y); o[2] = f2bf(v0.z); o[3] = f2bf(v0.w);
  o[4] = f2bf(v1.x); o[5] = f2bf(v1.y); o[6] = f2bf(v1.z); o[7] = f2bf(v1.w);
  *(u16x8*)(out + i) = o;
}

// ---------------------------------------------------------------------------
// Repack [3*KD, KD] fp32 weights -> per-8ch-block split-bf16 [SB][32][KD].
__global__ __launch_bounds__(256)
void repack_whh(const float* __restrict__ w_hh, unsigned short* __restrict__ hi,
                unsigned short* __restrict__ lo) {
  long long idx = ((long long)blockIdx.x * 256 + threadIdx.x) * 8;
  if (idx >= (long long)SB * 32 * KD) return;
  int k  = (int)(idx & (KD - 1));
  int rr = (int)(idx >> 10);
  int r = rr & 31, bid = rr >> 5;
  u16x8 h8 = (u16x8)0, l8 = (u16x8)0;
  if (r < 24) {
    int g = r >> 3, c = bid * 8 + (r & 7);
    const float* src = w_hh + ((size_t)(g * KD + c)) * KD + k;
    float4 v0 = *(const float4*)src, v1 = *(const float4*)(src + 4);
    float vv[8] = {v0.x, v0.y, v0.z, v0.w, v1.x, v1.y, v1.z, v1.w};
#pragma unroll
    for (int j = 0; j < 8; ++j) {
      unsigned short h = f2bf(vv[j]);
      h8[j] = h;
      l8[j] = f2bf(vv[j] - bf2f(h));
    }
  }
  *(u16x8*)(hi + idx) = h8;
  *(u16x8*)(lo + idx) = l8;
}

// Same packing, single bf16 (w_ih1 for the on-the-fly x-projection).
__global__ __launch_bounds__(256)
void repack_w_single(const float* __restrict__ w, unsigned short* __restrict__ pk) {
  long long idx = ((long long)blockIdx.x * 256 + threadIdx.x) * 8;
  if (idx >= (long long)SB * 32 * KD) return;
  int k  = (int)(idx & (KD - 1));
  int rr = (int)(idx >> 10);
  int r = rr & 31, bid = rr >> 5;
  u16x8 h8 = (u16x8)0;
  if (r < 24) {
    int g = r >> 3, c = bid * 8 + (r & 7);
    const float* src = w + ((size_t)(g * KD + c)) * KD + k;
    float4 v0 = *(const float4*)src, v1 = *(const float4*)(src + 4);
    float vv[8] = {v0.x, v0.y, v0.z, v0.w, v1.x, v1.y, v1.z, v1.w};
#pragma unroll
    for (int j = 0; j < 8; ++j) h8[j] = f2bf(vv[j]);
  }
  *(u16x8*)(pk + idx) = h8;
}

// ---------------------------------------------------------------------------
// bf16 MFMA GEMM (validated R2/R7): C[m,n] = sum_k A[m,k]*W[n,k] + bias[n].
// SWZ=1: 1D grid with bijective XCD-chunk swizzle (validated R16: -11% FETCH).
template<int GATHER, int OUTMODE, int SWZ>
__global__ __launch_bounds__(256)
void gemm_bf16(const unsigned short* __restrict__ A,
               const unsigned short* __restrict__ W,
               const float* __restrict__ bias, float* __restrict__ C, int Ndim,
               const int* __restrict__ seq,
               const unsigned short* __restrict__ start_bf,
               const unsigned short* __restrict__ table_bf) {
  __shared__ __align__(16) unsigned short a_s[128 * 32];
  __shared__ __align__(16) unsigned short b_s[128 * 32];
  const int tid  = threadIdx.x;
  const int lane = tid & 63;
  const int wave = tid >> 6;
  int m0, n0;
  if (SWZ) {
    const int nwg = gridDim.x;
    const int q = nwg >> 3, r8 = nwg & 7;
    const int xcd = blockIdx.x & 7, oidx = blockIdx.x >> 3;
    const int wgid = (xcd < r8 ? xcd * (q + 1) : r8 * (q + 1) + (xcd - r8) * q) + oidx;
    const int nby = Ndim >> 7;
    m0 = (wgid / nby) * 128;
    n0 = (wgid % nby) * 128;
  } else {
    m0 = blockIdx.x * 128;
    n0 = blockIdx.y * 128;
  }
  const int wr = wave >> 1, wc = wave & 1;

  f32x4 acc[4][4];
#pragma unroll
  for (int i = 0; i < 4; ++i)
#pragma unroll
    for (int j = 0; j < 4; ++j) acc[i][j] = (f32x4){0.f, 0.f, 0.f, 0.f};

  const int lrow = lane & 15;
  const int lkhi = lane >> 4;

  for (int kt = 0; kt < KD; kt += 32) {
    __syncthreads();
#pragma unroll
    for (int j = 0; j < 2; ++j) {
      int flat = tid * 16 + j * 4096;
      int row = flat >> 6;
      int cc = (flat >> 4) & 3;
      const unsigned short* src;
      if (GATHER) {
        int m = m0 + row; if (m >= M) m = 0;
        int t = m / B, b = m - t * B;
        const unsigned short* rowsrc =
            (t == 0) ? start_bf : (table_bf + (size_t)seq[b * L + t - 1] * KD);
        src = rowsrc + kt + cc * 8;
      } else {
        int m = m0 + row; if (m >= M) m = 0;
        src = A + (size_t)m * KD + kt + cc * 8;
      }
      *(int4*)((char*)a_s + flat) = *(const int4*)src;
    }
#pragma unroll
    for (int j = 0; j < 2; ++j) {
      int flat = tid * 16 + j * 4096;
      int row = flat >> 6;
      int cc = (flat >> 4) & 3;
      const unsigned short* src = W + (size_t)(n0 + row) * KD + kt + cc * 8;
      *(int4*)((char*)b_s + flat) = *(const int4*)src;
    }
    __syncthreads();

    s16x8 af[4], wf[4];
#pragma unroll
    for (int i = 0; i < 4; ++i) {
      int arow = wr * 64 + i * 16 + lrow;
      af[i] = *(const s16x8*)((const char*)a_s + arow * 64 + lkhi * 16);
      int brow = wc * 64 + i * 16 + lrow;
      wf[i] = *(const s16x8*)((const char*)b_s + brow * 64 + lkhi * 16);
    }
#pragma unroll
    for (int i = 0; i < 4; ++i)
#pragma unroll
      for (int j = 0; j < 4; ++j)
        acc[i][j] = __builtin_amdgcn_mfma_f32_16x16x32_bf16(af[i], wf[j],
                                                            acc[i][j], 0, 0, 0);
  }

#pragma unroll
  for (int i = 0; i < 4; ++i) {
#pragma unroll
    for (int r = 0; r < 4; ++r) {
      int m = m0 + wr * 64 + i * 16 + (lane >> 4) * 4 + r;
      if (m >= M) continue;
      size_t rowoff;
      if (OUTMODE == 0) {
        rowoff = (size_t)m * (size_t)Ndim;
      } else {
        int t = m / B, b = m - t * B;
        rowoff = ((size_t)b * T + t) * (size_t)Ndim;
      }
#pragma unroll
      for (int j = 0; j < 4; ++j) {
        int n = n0 + wc * 64 + j * 16 + (lane & 15);
        C[rowoff + n] = acc[i][j][r] + bias[n];
      }
    }
  }
}

// ---------------------------------------------------------------------------
// Per-step pipelined GRU kernel: 8 channels/block, 256 blocks, 512 threads
// (8 waves, K-eighth each). h exchanged as bf16-HI ONLY (R17 lesson: the
// fp32 state is block-private & exact, so hi-quantization doesn't accumulate;
// the L1 x-input has been hi-only since R7 at absmax 0.0039). W stays fp24
// via hi+lo (L2-cached, no exchange cost): acc = h_hi*W_hi + h_hi*W_lo.
// Blocks [0,SB): layer0 step t. Blocks [SB,2SB): layer1 step t-1.
__global__ __launch_bounds__(512)
void gru_pipe(int t, const float* __restrict__ xp0,
              const unsigned short* __restrict__ wpk0_hi,
              const unsigned short* __restrict__ wpk0_lo,
              const float* __restrict__ b_hh0,
              const unsigned short* __restrict__ wpk1_hi,
              const unsigned short* __restrict__ wpk1_lo,
              const unsigned short* __restrict__ wih1pk,
              const float* __restrict__ b_ih1,
              const float* __restrict__ b_hh1,
              const unsigned short* __restrict__ h0hi,
              const float* __restrict__ h0f,
              unsigned short* __restrict__ ys0_bf,
              float* __restrict__ h0f32,
              unsigned short* __restrict__ ys1_bf,
              float* __restrict__ h1f32) {
  __shared__ float cp[8][48 * 33];   // 50688 B
  const int tid = threadIdx.x;
  const bool is1 = blockIdx.x >= SB;
  const int bid = is1 ? (int)blockIdx.x - SB : (int)blockIdx.x;
  const int c0 = bid * 8;
  const int lane = tid & 63, wave = tid >> 6;   // 8 waves, K-eighth each
  const int lrow = lane & 15, lkhi = lane >> 4;

  int s = is1 ? t - 1 : t;
  if (is1 ? (s < 0) : (s >= T)) return;

  const unsigned short* wb_hi = (is1 ? wpk1_hi : wpk0_hi) + (size_t)bid * 32 * KD;
  const unsigned short* wb_lo = (is1 ? wpk1_lo : wpk0_lo) + (size_t)bid * 32 * KD;
  const unsigned short* wb_wx = wih1pk + (size_t)bid * 32 * KD;
  const float* bhh = is1 ? b_hh1 : b_hh0;

  const unsigned short *Shi, *Xhi = nullptr;
  const float *hold, *xp_t = nullptr;
  float* hnew_p;
  unsigned short* yhi;
  if (!is1) {
    Shi = (s == 0) ? h0hi : ys0_bf + (size_t)(s - 1) * B * KD;
    hold = (s == 0) ? h0f : h0f32;
    hnew_p = h0f32;
    yhi = ys0_bf + (size_t)s * B * KD;
    xp_t = xp0 + (size_t)s * B * G3;
  } else {
    Shi = (s == 0) ? h0hi : ys1_bf + (size_t)(s - 1) * B * KD;
    hold = (s == 0) ? h0f : h1f32;
    hnew_p = h1f32;
    yhi = ys1_bf + (size_t)s * B * KD;
    Xhi = ys0_bf + (size_t)s * B * KD;
  }

  // w-rows for the two 16-row n-tiles (24 real rows, clamp pad)
  int rB0 = lrow;
  int rB1 = 16 + lrow; if (rB1 > 23) rB1 = 23;

  f32x4 acc_h[3][2], acc_x[3][2];
#pragma unroll
  for (int mt = 0; mt < 3; ++mt)
#pragma unroll
    for (int nt = 0; nt < 2; ++nt) {
      acc_h[mt][nt] = (f32x4){0.f, 0.f, 0.f, 0.f};
      acc_x[mt][nt] = (f32x4){0.f, 0.f, 0.f, 0.f};
    }

#pragma unroll
  for (int ks = 0; ks < 4; ++ks) {
    int k0 = wave * 128 + ks * 32 + lkhi * 8;
    s16x8 ah[3], xh[3];
#pragma unroll
    for (int mt = 0; mt < 3; ++mt) {
      size_t hoff = (size_t)(mt * 16 + lrow) * KD + k0;
      ah[mt] = *(const s16x8*)(Shi + hoff);
      if (is1) xh[mt] = *(const s16x8*)(Xhi + hoff);
    }
    s16x8 bh[2], bl[2], wx[2];
    {
      size_t o0 = (size_t)rB0 * KD + k0, o1 = (size_t)rB1 * KD + k0;
      bh[0] = *(const s16x8*)(wb_hi + o0); bh[1] = *(const s16x8*)(wb_hi + o1);
      bl[0] = *(const s16x8*)(wb_lo + o0); bl[1] = *(const s16x8*)(wb_lo + o1);
      if (is1) { wx[0] = *(const s16x8*)(wb_wx + o0); wx[1] = *(const s16x8*)(wb_wx + o1); }
    }
#pragma unroll
    for (int mt = 0; mt < 3; ++mt)
#pragma unroll
      for (int nt = 0; nt < 2; ++nt) {
        acc_h[mt][nt] = __builtin_amdgcn_mfma_f32_16x16x32_bf16(ah[mt], bh[nt], acc_h[mt][nt], 0, 0, 0);
        acc_h[mt][nt] = __builtin_amdgcn_mfma_f32_16x16x32_bf16(ah[mt], bl[nt], acc_h[mt][nt], 0, 0, 0);
        if (is1)
          acc_x[mt][nt] = __builtin_amdgcn_mfma_f32_16x16x32_bf16(xh[mt], wx[nt], acc_x[mt][nt], 0, 0, 0);
      }
  }

  // phase 1: h partials -> cp[wave]
#pragma unroll
  for (int mt = 0; mt < 3; ++mt)
#pragma unroll
    for (int nt = 0; nt < 2; ++nt)
#pragma unroll
      for (int r = 0; r < 4; ++r) {
        int row = mt * 16 + (lane >> 4) * 4 + r;
        cp[wave][row * 33 + nt * 16 + (lane & 15)] = acc_h[mt][nt][r];
      }
  __syncthreads();
  float ph[3] = {0.f, 0.f, 0.f};
  if (tid < 384) {
    int b = tid >> 3, c = tid & 7;
#pragma unroll
    for (int w = 0; w < 8; ++w) {
      ph[0] += cp[w][b * 33 + c];
      ph[1] += cp[w][b * 33 + 8 + c];
      ph[2] += cp[w][b * 33 + 16 + c];
    }
  }
  // phase 2 (layer1 only): x partials through the same cp buffer
  float px[3] = {0.f, 0.f, 0.f};
  if (is1) {
    __syncthreads();
#pragma unroll
    for (int mt = 0; mt < 3; ++mt)
#pragma unroll
      for (int nt = 0; nt < 2; ++nt)
#pragma unroll
        for (int r = 0; r < 4; ++r) {
          int row = mt * 16 + (lane >> 4) * 4 + r;
          cp[wave][row * 33 + nt * 16 + (lane & 15)] = acc_x[mt][nt][r];
        }
    __syncthreads();
    if (tid < 384) {
      int b = tid >> 3, c = tid & 7;
#pragma unroll
      for (int w = 0; w < 8; ++w) {
        px[0] += cp[w][b * 33 + c];
        px[1] += cp[w][b * 33 + 8 + c];
        px[2] += cp[w][b * 33 + 16 + c];
      }
    }
  }

  // gate + state update: 384 (b,c) pairs
  if (tid < 384) {
    int b = tid >> 3, c = tid & 7;
    int gc = c0 + c;
    float xr, xz, xn;
    if (is1) {
      xr = px[0] + b_ih1[gc];
      xz = px[1] + b_ih1[KD + gc];
      xn = px[2] + b_ih1[2 * KD + gc];
    } else {
      const float* xrow = xp_t + (size_t)b * G3;
      xr = xrow[gc]; xz = xrow[KD + gc]; xn = xrow[2 * KD + gc];
    }
    float hr = ph[0] + bhh[gc];
    float hz = ph[1] + bhh[KD + gc];
    float hn = ph[2] + bhh[2 * KD + gc];
    float r_ = 1.f / (1.f + expf(-(xr + hr)));
    float z_ = 1.f / (1.f + expf(-(xz + hz)));
    float n_ = tanhf(xn + r_ * hn);
    float hv = hold[(size_t)b * KD + gc];
    float hnew = (1.f - z_) * n_ + z_ * hv;
    hnew_p[(size_t)b * KD + gc] = hnew;
    yhi[(size_t)b * KD + gc] = f2bf(hnew);
  }
}

// ---------------------------------------------------------------------------
__global__ __launch_bounds__(256)
void softmax_mask(float* __restrict__ out, const int* __restrict__ seq) {
  const int t = blockIdx.x, b = blockIdx.y;
  float* row = out + ((size_t)b * T + t) * V;
  __shared__ unsigned bits[V / 32];
  __shared__ float red[4];
  const int tid = threadIdx.x;
  const bool masked = (t < L - 1);
  if (masked) {
    bits[tid] = 0u;
    __syncthreads();
    int rem = L - t;
    if (tid < rem) {
      int id = seq[b * L + t + tid];
      atomicOr(&bits[id >> 5], 1u << (id & 31));
    }
  }
  __syncthreads();

  float4 x[8];
  float mx = -3.0e38f;
#pragma unroll
  for (int j = 0; j < 8; ++j) {
    float4 v = ((const float4*)row)[j * 256 + tid];
    if (masked) {
      int vb = (j * 256 + tid) * 4;
      unsigned wrd = bits[vb >> 5];
      int sh = vb & 31;
      if (!((wrd >> (sh + 0)) & 1u)) v.x = -1.0e30f;
      if (!((wrd >> (sh + 1)) & 1u)) v.y = -1.0e30f;
      if (!((wrd >> (sh + 2)) & 1u)) v.z = -1.0e30f;
      if (!((wrd >> (sh + 3)) & 1u)) v.w = -1.0e30f;
    }
    x[j] = v;
    mx = fmaxf(mx, fmaxf(fmaxf(v.x, v.y), fmaxf(v.z, v.w)));
  }
#pragma unroll
  for (int off = 32; off > 0; off >>= 1) mx = fmaxf(mx, __shfl_xor(mx, off));
  int wv = tid >> 6;
  if ((tid & 63) == 0) red[wv] = mx;
  __syncthreads();
  mx = fmaxf(fmaxf(red[0], red[1]), fmaxf(red[2], red[3]));

  float s = 0.f;
#pragma unroll
  for (int j = 0; j < 8; ++j) {
    x[j].x = expf(x[j].x - mx); x[j].y = expf(x[j].y - mx);
    x[j].z = expf(x[j].z - mx); x[j].w = expf(x[j].w - mx);
    s += x[j].x + x[j].y + x[j].z + x[j].w;
  }
#pragma unroll
  for (int off = 32; off > 0; off >>= 1) s += __shfl_xor(s, off);
  __syncthreads();
  if ((tid & 63) == 0) red[wv] = s;
  __syncthreads();
  s = red[0] + red[1] + red[2] + red[3];
  float inv = 1.f / s;
#pragma unroll
  for (int j = 0; j < 8; ++j) {
    float4 v = make_float4(x[j].x * inv, x[j].y * inv, x[j].z * inv, x[j].w * inv);
    ((float4*)row)[j * 256 + tid] = v;
  }
}

// ---------------------------------------------------------------------------
extern "C" void kernel_launch(void* const* d_in, const int* in_sizes, int n_in,
                              void* d_out, int out_size, void* d_ws, size_t ws_size,
                              hipStream_t stream) {
  const float* event_table = (const float*)d_in[0];
  const float* user_table  = (const float*)d_in[1];
  const float* startv      = (const float*)d_in[2];
  const float* w_ih0 = (const float*)d_in[3];
  const float* w_hh0 = (const float*)d_in[4];
  const float* b_ih0 = (const float*)d_in[5];
  const float* b_hh0 = (const float*)d_in[6];
  const float* w_ih1 = (const float*)d_in[7];
  const float* w_hh1 = (const float*)d_in[8];
  const float* b_ih1 = (const float*)d_in[9];
  const float* b_hh1 = (const float*)d_in[10];
  const float* lin_w = (const float*)d_in[11];
  const float* lin_b = (const float*)d_in[12];
  const int*   ids   = (const int*)d_in[13];
  const int*   seq   = (const int*)d_in[14];
  float* out = (float*)d_out;

  // workspace layout (~230 MB)
  float* xp0  = (float*)d_ws;                           // M*G3 f32
  float* h0f  = xp0 + (size_t)M * G3;                   // B*KD
  float* h0f32 = h0f + (size_t)B * KD;                  // B*KD (layer0 state)
  float* h1f32 = h0f32 + (size_t)B * KD;                // B*KD (layer1 state)
  unsigned short* ut_bf    = (unsigned short*)(h1f32 + (size_t)B * KD);
  unsigned short* start_bf = ut_bf    + (size_t)V * KD;
  unsigned short* wih0_bf  = start_bf + KD;
  unsigned short* linw_bf  = wih0_bf  + (size_t)G3 * KD;
  unsigned short* ys0_bf   = linw_bf  + (size_t)V * KD;
  unsigned short* ys1_bf   = ys0_bf   + (size_t)M * KD;
  unsigned short* h0hi     = ys1_bf   + (size_t)M * KD;
  unsigned short* wpk0_hi  = h0hi + (size_t)B * KD;
  unsigned short* wpk0_lo  = wpk0_hi + (size_t)SB * 32 * KD;
  unsigned short* wpk1_hi  = wpk0_lo + (size_t)SB * 32 * KD;
  unsigned short* wpk1_lo  = wpk1_hi + (size_t)SB * 32 * KD;
  unsigned short* wih1pk   = wpk1_lo + (size_t)SB * 32 * KD;

  init_h0<<<dim3(B), 256, 0, stream>>>(event_table, ids, h0f, h0hi);

  auto cvt = [&](const float* src, unsigned short* dst, long long n) {
    int blocks = (int)((n + 2047) / 2048);
    cvt_bf16<<<dim3(blocks), 256, 0, stream>>>(src, dst, n);
  };
  cvt(user_table, ut_bf,    (long long)V * KD);
  cvt(startv,     start_bf, KD);
  cvt(w_ih0,      wih0_bf,  (long long)G3 * KD);
  cvt(lin_w,      linw_bf,  (long long)V * KD);

  repack_whh<<<dim3(SB * 32 * KD / 2048), 256, 0, stream>>>(w_hh0, wpk0_hi, wpk0_lo);
  repack_whh<<<dim3(SB * 32 * KD / 2048), 256, 0, stream>>>(w_hh1, wpk1_hi, wpk1_lo);
  repack_w_single<<<dim3(SB * 32 * KD / 2048), 256, 0, stream>>>(w_ih1, wih1pk);

  // layer 0 input projection (gather from bf16 tables), 1D XCD-swizzled grid
  gemm_bf16<1, 0, 1><<<dim3(((M + 127) / 128) * (G3 / 128)), 256, 0, stream>>>(
      nullptr, wih0_bf, b_ih0, xp0, G3, seq, start_bf, ut_bf);

  // pipelined two-layer scan: T+1 launches, 256 blocks x 512 threads
  for (int t = 0; t <= T; ++t) {
    gru_pipe<<<dim3(2 * SB), dim3(512), 0, stream>>>(
        t, xp0, wpk0_hi, wpk0_lo, b_hh0, wpk1_hi, wpk1_lo, wih1pk, b_ih1, b_hh1,
        h0hi, h0f, ys0_bf, h0f32, ys1_bf, h1f32);
  }

  // logits into d_out at [b][t][v], 1D XCD-swizzled grid (validated R16)
  gemm_bf16<0, 1, 1><<<dim3(((M + 127) / 128) * (V / 128)), 256, 0, stream>>>(
      ys1_bf, linw_bf, lin_b, out, V, nullptr, nullptr, nullptr);

  // masked softmax in place
  softmax_mask<<<dim3(T, B), 256, 0, stream>>>(out, seq);
}